// Round 1
// 678.212 us; speedup vs baseline: 1.0069x; 1.0069x over previous
//
#include <hip/hip_runtime.h>
#include <hip/hip_bf16.h>
#include <math.h>

typedef unsigned short u16;
typedef unsigned int u32;
typedef __attribute__((ext_vector_type(8))) __bf16 bf16x8;
typedef __attribute__((ext_vector_type(4))) float f32x4;
typedef __attribute__((ext_vector_type(4))) u32 u32x4;

#define NNODES 50000
#define NEDGES 800000

__device__ __forceinline__ float bf2f(u16 u) {
    union { u32 i; float f; } v; v.i = ((u32)u) << 16; return v.f;
}
__device__ __forceinline__ u16 f2bf(float x) {
    union { float f; u32 i; } v; v.f = x;
    u32 r = v.i + 0x7fffu + ((v.i >> 16) & 1u);
    return (u16)(r >> 16);
}
__device__ __forceinline__ float lrelu(float x) { return x >= 0.f ? x : 0.2f * x; }

// ---------------- CSR build ----------------
__global__ __launch_bounds__(256) void k_zero(int* a, int count) {
    int i = blockIdx.x * 256 + threadIdx.x;
    if (i < count) a[i] = 0;
}

__global__ __launch_bounds__(256) void k_count(const int* __restrict__ dst, int* __restrict__ counts, int e) {
    int i = blockIdx.x * 256 + threadIdx.x;
    if (i < e) atomicAdd(&counts[dst[i]], 1);
}

__global__ __launch_bounds__(256) void k_scan1(const int* __restrict__ counts, int* __restrict__ row_ptr,
                                               int* __restrict__ bsums, int n) {
    __shared__ int tmp[256];
    int t = threadIdx.x, i = blockIdx.x * 256 + t;
    int v = (i < n) ? counts[i] : 0;
    tmp[t] = v; __syncthreads();
    for (int off = 1; off < 256; off <<= 1) {
        int x = 0; if (t >= off) x = tmp[t - off];
        __syncthreads(); tmp[t] += x; __syncthreads();
    }
    if (i < n) row_ptr[i] = tmp[t] - v;
    if (t == 255) bsums[blockIdx.x] = tmp[255];
}

__global__ __launch_bounds__(256) void k_scan2(int* bsums, int nb) {
    __shared__ int tmp[256];
    int t = threadIdx.x;
    int v = (t < nb) ? bsums[t] : 0;
    tmp[t] = v; __syncthreads();
    for (int off = 1; off < 256; off <<= 1) {
        int x = 0; if (t >= off) x = tmp[t - off];
        __syncthreads(); tmp[t] += x; __syncthreads();
    }
    if (t < nb) bsums[t] = tmp[t] - v;
}

__global__ __launch_bounds__(256) void k_scan3(int* __restrict__ row_ptr, const int* __restrict__ bsums,
                                               int n, int total) {
    int i = blockIdx.x * 256 + threadIdx.x;
    if (i < n) row_ptr[i] += bsums[blockIdx.x];
    if (i == 0) row_ptr[n] = total;
}

__global__ __launch_bounds__(256) void k_fill(const int* __restrict__ src, const int* __restrict__ dst,
                                              const int* __restrict__ row_ptr, int* __restrict__ cursor,
                                              int* __restrict__ esrc, int e) {
    int i = blockIdx.x * 256 + threadIdx.x;
    if (i < e) {
        int d = dst[i];
        int p = row_ptr[d] + atomicAdd(&cursor[d], 1);
        esrc[p] = src[i];
    }
}

// ---------------- weight transpose+cast f32[K,N] -> bf16[N,K] ----------------
__global__ __launch_bounds__(256) void k_transpose(const float* __restrict__ W, u16* __restrict__ Wt, int K, int Nn) {
    int i = blockIdx.x * 256 + threadIdx.x;
    if (i < K * Nn) { int k = i / Nn, n = i % Nn; Wt[n * K + k] = f2bf(W[i]); }
}

// ---------------- layer-2 algebraic prep ----------------
// ul[h*128+k] = sum_f W2[k, h*128+f] * al2[h,f]  (attention-logit projection folded through W2)
// ur likewise with ar2. bmean[c] = 0.5*(b2[c]+b2[128+c]) (head-mean of bias).
__global__ __launch_bounds__(256) void k_attnvec(const float* __restrict__ W2, const float* __restrict__ al2,
                                                 const float* __restrict__ ar2, const float* __restrict__ b2,
                                                 float* __restrict__ ul, float* __restrict__ ur,
                                                 float* __restrict__ bmean) {
    int t = threadIdx.x;
    int h = t >> 7, k = t & 127;
    const float* wrow = W2 + (size_t)k * 256 + h * 128;
    const float* alh = al2 + h * 128;
    const float* arh = ar2 + h * 128;
    float sl = 0.f, sr = 0.f;
    for (int f = 0; f < 128; f += 4) {
        f32x4 w = *(const f32x4*)(wrow + f);
        f32x4 a = *(const f32x4*)(alh + f);
        f32x4 r = *(const f32x4*)(arh + f);
#pragma unroll
        for (int q = 0; q < 4; q++) { sl += w[q] * a[q]; sr += w[q] * r[q]; }
    }
    ul[t] = sl; ur[t] = sr;
    if (t < 128) bmean[t] = 0.5f * (b2[t] + b2[128 + t]);
}

// Wct[f*256 + (h*128+k)] = bf16(0.5 * W2[k, h*128+f])  -- combined head-mean weight, transposed for GEMM-Bt
__global__ __launch_bounds__(256) void k_makeWc(const float* __restrict__ W2, u16* __restrict__ Wct) {
    int i = blockIdx.x * 256 + threadIdx.x;
    if (i < 128 * 256) {
        int f = i >> 8, c = i & 255, h = c >> 7, k = c & 127;
        Wct[i] = f2bf(0.5f * W2[(size_t)k * 256 + h * 128 + f]);
    }
}

// ---------------- A-fragment loaders (f32 or bf16 source) ----------------
__device__ __forceinline__ void load_af(const float* __restrict__ arow, int k0, int K, bf16x8& a) {
    if (k0 + 8 <= K) {
        f32x4 a0 = *(const f32x4*)(arow + k0);
        f32x4 a1 = *(const f32x4*)(arow + k0 + 4);
#pragma unroll
        for (int j = 0; j < 4; j++) { a[j] = (__bf16)a0[j]; a[4 + j] = (__bf16)a1[j]; }
    } else {
#pragma unroll
        for (int j = 0; j < 8; j++) a[j] = (__bf16)0.f;
    }
}
__device__ __forceinline__ void load_af(const u16* __restrict__ arow, int k0, int K, bf16x8& a) {
    if (k0 + 8 <= K) a = *(const bf16x8*)(arow + k0);
    else {
#pragma unroll
        for (int j = 0; j < 8; j++) a[j] = (__bf16)0.f;
    }
}

// ---------------- Tiled MFMA GEMM: C[M,Nn](bf16) = A[M,K] * Bt[Nn,K]^T ----------------
// EPI: C = f2bf(acc + bias[col] + bf2f(resid[row*Nn+col]))  (layer-2 head-mean bias + residual)
template <typename AT, bool EPI>
__global__ __launch_bounds__(256) void k_gemm_tiled(const AT* __restrict__ A, const u16* __restrict__ Bt,
                                                    u16* __restrict__ C, int M, int Nn, int K,
                                                    const float* __restrict__ bias,
                                                    const u16* __restrict__ resid) {
    __shared__ __align__(16) u16 lb[2][128 * 40];
    const int tid = threadIdx.x;
    const int wave = tid >> 6, lane = tid & 63;
    const int m = lane & 15, quad = lane >> 4;
    const int row0 = blockIdx.x * 64 + wave * 16;
    const int col0 = blockIdx.y * 128;

    f32x4 acc[8];
#pragma unroll
    for (int t = 0; t < 8; t++)
#pragma unroll
        for (int r = 0; r < 4; r++) acc[t][r] = 0.f;

    int ar = row0 + m; if (ar > M - 1) ar = M - 1;   // clamp OOB rows (stores guarded)
    const AT* arow = A + (size_t)ar * K;
    const int scol = tid & 127;          // staging col
    const int sseg = (tid >> 7) * 16;    // staging k-base within tile (0 or 16)
    const u16* bcol = Bt + (size_t)(col0 + scol) * K;

    const int nsteps = (K + 31) >> 5;

#pragma unroll
    for (int p = 0; p < 2; ++p) {
        int kl = sseg + p * 8;
        u32x4 v = 0;
        if (kl < K) v = *(const u32x4*)(bcol + kl);
        *(u32x4*)&lb[0][scol * 40 + kl] = v;
    }
    bf16x8 acur, anext;
    load_af(arow, quad * 8, K, acur);
    __syncthreads();

    for (int s = 0; s < nsteps; ++s) {
        const int buf = s & 1;
        if (s + 1 < nsteps) {
            const int k0n = (s + 1) * 32;
            load_af(arow, k0n + quad * 8, K, anext);
#pragma unroll
            for (int p = 0; p < 2; ++p) {
                int kl = sseg + p * 8;
                u32x4 v = 0;
                if (k0n + kl < K) v = *(const u32x4*)(bcol + k0n + kl);
                *(u32x4*)&lb[buf ^ 1][scol * 40 + kl] = v;
            }
        }
#pragma unroll
        for (int t = 0; t < 8; ++t) {
            bf16x8 b = *(const bf16x8*)&lb[buf][(t * 16 + m) * 40 + quad * 8];
            acc[t] = __builtin_amdgcn_mfma_f32_16x16x32_bf16(acur, b, acc[t], 0, 0, 0);
        }
        acur = anext;
        __syncthreads();
    }

#pragma unroll
    for (int t = 0; t < 8; t++)
#pragma unroll
        for (int r = 0; r < 4; r++) {
            int row = row0 + quad * 4 + r;
            int col = col0 + t * 16 + m;
            if (row < M) {
                float v = acc[t][r];
                if (EPI) v += bias[col] + bf2f(resid[(size_t)row * Nn + col]);
                C[(size_t)row * Nn + col] = f2bf(v);
            }
        }
}

// ---------------- small MFMA GEMM (bf16 A), one wave/block: N=32 mean/var ----------------
template <int NT>
__global__ __launch_bounds__(64) void k_gemm(const u16* __restrict__ A, const u16* __restrict__ Bt,
                                             u16* __restrict__ C, int M, int Nn, int K) {
    int row0 = blockIdx.x * 16;
    int col0 = blockIdx.y * (16 * NT);
    int lane = threadIdx.x;
    int m = lane & 15, quad = lane >> 4;
    f32x4 acc[NT];
#pragma unroll
    for (int t = 0; t < NT; t++)
#pragma unroll
        for (int r = 0; r < 4; r++) acc[t][r] = 0.f;

    const u16* arow = A + (size_t)(row0 + m) * K + quad * 8;
    int full = K >> 5;
    for (int s = 0; s < full; ++s) {
        bf16x8 a = *(const bf16x8*)(arow + s * 32);
#pragma unroll
        for (int t = 0; t < NT; t++) {
            bf16x8 b = *(const bf16x8*)(Bt + (size_t)(col0 + t * 16 + m) * K + s * 32 + quad * 8);
            acc[t] = __builtin_amdgcn_mfma_f32_16x16x32_bf16(a, b, acc[t], 0, 0, 0);
        }
    }
#pragma unroll
    for (int t = 0; t < NT; t++)
#pragma unroll
        for (int r = 0; r < 4; r++) {
            int row = row0 + quad * 4 + r;
            int col = col0 + t * 16 + m;
            if (row < M) C[(size_t)row * Nn + col] = f2bf(acc[t][r]);
        }
}

// ---------------- el/er projections ----------------
__global__ __launch_bounds__(256) void k_eler1(const u16* __restrict__ feat, const float* __restrict__ al,
                                               const float* __restrict__ ar, float* __restrict__ el,
                                               float* __restrict__ er, int n) {
    int node = blockIdx.x * 4 + (threadIdx.x >> 6);
    if (node >= n) return;
    int lane = threadIdx.x & 63;
    const u16* fr = feat + (size_t)node * 128;
    float f0 = bf2f(fr[lane]), f1 = bf2f(fr[64 + lane]);
    float pe = f0 * al[lane] + f1 * al[64 + lane];
    float pr = f0 * ar[lane] + f1 * ar[64 + lane];
#pragma unroll
    for (int off = 32; off; off >>= 1) { pe += __shfl_xor(pe, off); pr += __shfl_xor(pr, off); }
    if (lane == 0) { el[node] = pe; er[node] = pr; }
}

// layer-2 logits straight from o (128-dim) via folded vectors ul/ur [2][128]
__global__ __launch_bounds__(256) void k_eler2o(const u16* __restrict__ o_in, const float* __restrict__ ul,
                                                const float* __restrict__ ur, float* __restrict__ el,
                                                float* __restrict__ er, int n) {
    int node = blockIdx.x * 4 + (threadIdx.x >> 6);
    if (node >= n) return;
    int lane = threadIdx.x & 63;
    const u16* fr = o_in + (size_t)node * 128;
    float f0 = bf2f(fr[lane]), f1 = bf2f(fr[64 + lane]);
#pragma unroll
    for (int h = 0; h < 2; ++h) {
        float pe = f0 * ul[h * 128 + lane] + f1 * ul[h * 128 + 64 + lane];
        float pr = f0 * ur[h * 128 + lane] + f1 * ur[h * 128 + 64 + lane];
#pragma unroll
        for (int off = 32; off; off >>= 1) { pe += __shfl_xor(pe, off); pr += __shfl_xor(pr, off); }
        if (lane == 0) { el[node * 2 + h] = pe; er[node * 2 + h] = pr; }
    }
}

__global__ __launch_bounds__(256) void k_elermv(const u16* __restrict__ featm, const u16* __restrict__ featv,
                                                const float* __restrict__ alm, const float* __restrict__ arm,
                                                const float* __restrict__ alv, const float* __restrict__ arv,
                                                float* __restrict__ elm, float* __restrict__ erm,
                                                float* __restrict__ elv, float* __restrict__ erv, int n) {
    int node = blockIdx.x * 4 + (threadIdx.x >> 6);
    if (node >= n) return;
    int lane = threadIdx.x & 63;
    int tbl = lane >> 5, j = lane & 31;
    const u16* ft = tbl ? featv : featm;
    const float* al = tbl ? alv : alm;
    const float* ar = tbl ? arv : arm;
    float f = bf2f(ft[(size_t)node * 32 + j]);
    float pe = f * al[j], pr = f * ar[j];
#pragma unroll
    for (int off = 1; off < 16; off <<= 1) { pe += __shfl_xor(pe, off); pr += __shfl_xor(pr, off); }
    if ((lane & 15) == 0) {
        int h = (lane >> 4) & 1;
        float* el = tbl ? elv : elm; float* er = tbl ? erv : erm;
        el[node * 2 + h] = pe; er[node * 2 + h] = pr;
    }
}

// ---------------- aggregation: layer 1 (H=1,F=128), 4-wide pipelined gathers ----------------
__global__ __launch_bounds__(256) void k_agg1(const int* __restrict__ row_ptr, const int* __restrict__ esrc,
                                              const u16* __restrict__ feat, const float* __restrict__ el,
                                              const float* __restrict__ er, const float* __restrict__ bias,
                                              u16* __restrict__ o_bf, int n) {
    int node = blockIdx.x * 4 + (threadIdx.x >> 6);
    if (node >= n) return;
    int lane = threadIdx.x & 63;
    int beg = row_ptr[node], end = row_ptr[node + 1];
    float erd = er[node];
    float mx = -3.0e38f;
    for (int i = beg + lane; i < end; i += 64) mx = fmaxf(mx, el[esrc[i]]);
#pragma unroll
    for (int off = 32; off; off >>= 1) mx = fmaxf(mx, __shfl_xor(mx, off));
    float me = (end > beg) ? lrelu(mx + erd) : 0.f;
    float acc0 = 0.f, acc1 = 0.f, den = 0.f;
    for (int base = beg; base < end; base += 64) {
        int i = base + lane;
        float w = 0.f; int s = 0;
        if (i < end) { s = esrc[i]; w = expf(lrelu(el[s] + erd) - me); }
        den += w;
        int cnt = min(64, end - base);
        int j = 0;
        for (; j + 4 <= cnt; j += 4) {
            float w0 = __shfl(w, j), w1 = __shfl(w, j + 1), w2 = __shfl(w, j + 2), w3 = __shfl(w, j + 3);
            int s0 = __shfl(s, j), s1 = __shfl(s, j + 1), s2 = __shfl(s, j + 2), s3 = __shfl(s, j + 3);
            u32 p0 = ((const u32*)(feat + (size_t)s0 * 128))[lane];
            u32 p1 = ((const u32*)(feat + (size_t)s1 * 128))[lane];
            u32 p2 = ((const u32*)(feat + (size_t)s2 * 128))[lane];
            u32 p3 = ((const u32*)(feat + (size_t)s3 * 128))[lane];
            acc0 += w0 * bf2f((u16)(p0 & 0xffff)) + w1 * bf2f((u16)(p1 & 0xffff))
                  + w2 * bf2f((u16)(p2 & 0xffff)) + w3 * bf2f((u16)(p3 & 0xffff));
            acc1 += w0 * bf2f((u16)(p0 >> 16)) + w1 * bf2f((u16)(p1 >> 16))
                  + w2 * bf2f((u16)(p2 >> 16)) + w3 * bf2f((u16)(p3 >> 16));
        }
        for (; j < cnt; ++j) {
            float wj = __shfl(w, j);
            int sj = __shfl(s, j);
            u32 pv = ((const u32*)(feat + (size_t)sj * 128))[lane];
            acc0 += wj * bf2f((u16)(pv & 0xffff));
            acc1 += wj * bf2f((u16)(pv >> 16));
        }
    }
#pragma unroll
    for (int off = 32; off; off >>= 1) den += __shfl_xor(den, off);
    float inv = (den > 0.f) ? 1.f / den : 0.f;
    float o0 = acc0 * inv + bias[2 * lane];
    float o1 = acc1 * inv + bias[2 * lane + 1];
    u32 pv = (u32)f2bf(o0) | ((u32)f2bf(o1) << 16);
    ((u32*)(o_bf + (size_t)node * 128))[lane] = pv;
}

// ---------------- aggregation layer 2 over o (H=2 weights, 128-dim payload), 4-wide ----------------
// agg[node] = [ (sum_e a0*o[src])/d0 , (sum_e a1*o[src])/d1 ]  as [N,256] bf16.
// Projection through W2, head-mean, bias and residual are folded into the following GEMM epilogue.
__global__ __launch_bounds__(256) void k_agg2o(const int* __restrict__ row_ptr, const int* __restrict__ esrc,
                                               const u16* __restrict__ o_in, const float* __restrict__ el,
                                               const float* __restrict__ er, u16* __restrict__ agg, int n) {
    int node = blockIdx.x * 4 + (threadIdx.x >> 6);
    if (node >= n) return;
    int lane = threadIdx.x & 63;
    int beg = row_ptr[node], end = row_ptr[node + 1];
    float er0 = er[node * 2], er1 = er[node * 2 + 1];
    float mx0 = -3.0e38f, mx1 = -3.0e38f;
    for (int i = beg + lane; i < end; i += 64) {
        int s = esrc[i];
        float2 e2 = *(const float2*)(el + 2 * s);
        mx0 = fmaxf(mx0, e2.x); mx1 = fmaxf(mx1, e2.y);
    }
#pragma unroll
    for (int off = 32; off; off >>= 1) { mx0 = fmaxf(mx0, __shfl_xor(mx0, off)); mx1 = fmaxf(mx1, __shfl_xor(mx1, off)); }
    float me0 = (end > beg) ? lrelu(mx0 + er0) : 0.f;
    float me1 = (end > beg) ? lrelu(mx1 + er1) : 0.f;
    float a00 = 0.f, a01 = 0.f, a10 = 0.f, a11 = 0.f, d0 = 0.f, d1 = 0.f;
    for (int base = beg; base < end; base += 64) {
        int i = base + lane;
        float w0 = 0.f, w1 = 0.f; int s = 0;
        if (i < end) {
            s = esrc[i];
            float2 e2 = *(const float2*)(el + 2 * s);
            w0 = expf(lrelu(e2.x + er0) - me0);
            w1 = expf(lrelu(e2.y + er1) - me1);
        }
        d0 += w0; d1 += w1;
        int cnt = min(64, end - base);
        int j = 0;
        for (; j + 4 <= cnt; j += 4) {
            float w0a = __shfl(w0, j), w0b = __shfl(w0, j + 1), w0c = __shfl(w0, j + 2), w0d = __shfl(w0, j + 3);
            float w1a = __shfl(w1, j), w1b = __shfl(w1, j + 1), w1c = __shfl(w1, j + 2), w1d = __shfl(w1, j + 3);
            int sa = __shfl(s, j), sb = __shfl(s, j + 1), sc = __shfl(s, j + 2), sd = __shfl(s, j + 3);
            u32 pa = ((const u32*)(o_in + (size_t)sa * 128))[lane];
            u32 pb = ((const u32*)(o_in + (size_t)sb * 128))[lane];
            u32 pc = ((const u32*)(o_in + (size_t)sc * 128))[lane];
            u32 pd = ((const u32*)(o_in + (size_t)sd * 128))[lane];
            float la = bf2f((u16)(pa & 0xffff)), ha = bf2f((u16)(pa >> 16));
            float lb = bf2f((u16)(pb & 0xffff)), hb = bf2f((u16)(pb >> 16));
            float lc = bf2f((u16)(pc & 0xffff)), hc = bf2f((u16)(pc >> 16));
            float ld = bf2f((u16)(pd & 0xffff)), hd = bf2f((u16)(pd >> 16));
            a00 += w0a * la + w0b * lb + w0c * lc + w0d * ld;
            a01 += w0a * ha + w0b * hb + w0c * hc + w0d * hd;
            a10 += w1a * la + w1b * lb + w1c * lc + w1d * ld;
            a11 += w1a * ha + w1b * hb + w1c * hc + w1d * hd;
        }
        for (; j < cnt; ++j) {
            float w0j = __shfl(w0, j), w1j = __shfl(w1, j);
            int sj = __shfl(s, j);
            u32 pv = ((const u32*)(o_in + (size_t)sj * 128))[lane];
            float lo = bf2f((u16)(pv & 0xffff)), hi = bf2f((u16)(pv >> 16));
            a00 += w0j * lo; a01 += w0j * hi;
            a10 += w1j * lo; a11 += w1j * hi;
        }
    }
#pragma unroll
    for (int off = 32; off; off >>= 1) { d0 += __shfl_xor(d0, off); d1 += __shfl_xor(d1, off); }
    float i0 = (d0 > 0.f) ? 1.f / d0 : 0.f, i1 = (d1 > 0.f) ? 1.f / d1 : 0.f;
    u32 p0 = (u32)f2bf(a00 * i0) | ((u32)f2bf(a01 * i0) << 16);
    u32 p1 = (u32)f2bf(a10 * i1) | ((u32)f2bf(a11 * i1) << 16);
    u32* aw = (u32*)(agg + (size_t)node * 256);
    aw[lane] = p0;
    aw[64 + lane] = p1;
}

// ---------------- aggregation: mean & var fused (H=2,F=16), edge-parallel + reparameterize ----------------
__global__ __launch_bounds__(256) void k_aggmv(const int* __restrict__ row_ptr, const int* __restrict__ esrc,
                                               const u16* __restrict__ featm, const u16* __restrict__ featv,
                                               const float* __restrict__ elm, const float* __restrict__ erm,
                                               const float* __restrict__ elv, const float* __restrict__ erv,
                                               const float* __restrict__ bm, const float* __restrict__ bv,
                                               const float* __restrict__ eps, float* __restrict__ out, int n) {
    int node = blockIdx.x * 4 + (threadIdx.x >> 6);
    if (node >= n) return;
    int lane = threadIdx.x & 63;
    int f = lane & 15, h = (lane >> 4) & 1, tbl = lane >> 5;
    int beg = row_ptr[node], end = row_ptr[node + 1];
    float erm0 = erm[2 * node], erm1 = erm[2 * node + 1];
    float erv0 = erv[2 * node], erv1 = erv[2 * node + 1];
    float mm0 = -3.0e38f, mm1 = -3.0e38f, mv0 = -3.0e38f, mv1 = -3.0e38f;
    for (int i = beg + lane; i < end; i += 64) {
        int s = esrc[i];
        float2 em = *(const float2*)(elm + 2 * s);
        float2 ev = *(const float2*)(elv + 2 * s);
        mm0 = fmaxf(mm0, em.x); mm1 = fmaxf(mm1, em.y);
        mv0 = fmaxf(mv0, ev.x); mv1 = fmaxf(mv1, ev.y);
    }
#pragma unroll
    for (int off = 32; off; off >>= 1) {
        mm0 = fmaxf(mm0, __shfl_xor(mm0, off)); mm1 = fmaxf(mm1, __shfl_xor(mm1, off));
        mv0 = fmaxf(mv0, __shfl_xor(mv0, off)); mv1 = fmaxf(mv1, __shfl_xor(mv1, off));
    }
    float mem0 = (end > beg) ? lrelu(mm0 + erm0) : 0.f;
    float mem1 = (end > beg) ? lrelu(mm1 + erm1) : 0.f;
    float mev0 = (end > beg) ? lrelu(mv0 + erv0) : 0.f;
    float mev1 = (end > beg) ? lrelu(mv1 + erv1) : 0.f;

    const u16* ftp = tbl ? featv : featm;
    const int fidx = h * 16 + f;
    float accv = 0.f;
    float dm0 = 0.f, dm1 = 0.f, dv0 = 0.f, dv1 = 0.f;
    for (int base = beg; base < end; base += 64) {
        int i = base + lane;
        float wm0 = 0.f, wm1 = 0.f, wv0 = 0.f, wv1 = 0.f; int s = 0;
        if (i < end) {
            s = esrc[i];
            float2 em = *(const float2*)(elm + 2 * s);
            float2 ev = *(const float2*)(elv + 2 * s);
            wm0 = expf(lrelu(em.x + erm0) - mem0);
            wm1 = expf(lrelu(em.y + erm1) - mem1);
            wv0 = expf(lrelu(ev.x + erv0) - mev0);
            wv1 = expf(lrelu(ev.y + erv1) - mev1);
        }
        dm0 += wm0; dm1 += wm1; dv0 += wv0; dv1 += wv1;
        int cnt = min(64, end - base);
        for (int j = 0; j < cnt; ++j) {
            int sj = __shfl(s, j);
            float bm0 = __shfl(wm0, j);   // unconditional broadcasts (converged)
            float bm1 = __shfl(wm1, j);
            float bv0 = __shfl(wv0, j);
            float bv1 = __shfl(wv1, j);
            float wj = tbl ? (h ? bv1 : bv0) : (h ? bm1 : bm0);  // local select, safe
            accv += wj * bf2f(ftp[(size_t)sj * 32 + fidx]);
        }
    }
#pragma unroll
    for (int off = 32; off; off >>= 1) {
        dm0 += __shfl_xor(dm0, off); dm1 += __shfl_xor(dm1, off);
        dv0 += __shfl_xor(dv0, off); dv1 += __shfl_xor(dv1, off);
    }
    float den = tbl ? (h ? dv1 : dv0) : (h ? dm1 : dm0);
    float inv = (den > 0.f) ? 1.f / den : 0.f;
    float biasc = tbl ? bv[fidx] : bm[fidx];
    float outc = accv * inv + biasc;
    float hm = 0.5f * (outc + __shfl_xor(outc, 16));  // mean over the 2 heads (same tbl)
    float meanv = __shfl(hm, f);                      // tbl=0 lane
    float varp = __shfl(hm, 32 + f);                  // tbl=1 lane
    if (lane < 16) {
        float var = expf(varp);
        float z = meanv + sqrtf(var) * eps[(size_t)node * 16 + f];
        size_t base = (size_t)node * 16 + f;
        out[base] = z;
        out[(size_t)NNODES * 16 + base] = meanv;
        out[(size_t)2 * NNODES * 16 + base] = var;
    }
}

// ---------------- host ----------------
extern "C" void kernel_launch(void* const* d_in, const int* in_sizes, int n_in,
                              void* d_out, int out_size, void* d_ws, size_t ws_size,
                              hipStream_t stream) {
    const int N = NNODES, E = NEDGES;
    const float* x   = (const float*)d_in[0];
    const int* src   = (const int*)d_in[1];
    const int* dst   = (const int*)d_in[2];
    const float* W1  = (const float*)d_in[3];
    const float* al1 = (const float*)d_in[4];
    const float* ar1 = (const float*)d_in[5];
    const float* b1  = (const float*)d_in[6];
    const float* W2  = (const float*)d_in[7];
    const float* al2 = (const float*)d_in[8];
    const float* ar2 = (const float*)d_in[9];
    const float* b2  = (const float*)d_in[10];
    const float* Wm  = (const float*)d_in[11];
    const float* alm = (const float*)d_in[12];
    const float* arm = (const float*)d_in[13];
    const float* bm  = (const float*)d_in[14];
    const float* Wv  = (const float*)d_in[15];
    const float* alv = (const float*)d_in[16];
    const float* arv = (const float*)d_in[17];
    const float* bv  = (const float*)d_in[18];
    const float* eps = (const float*)d_in[19];
    float* out = (float*)d_out;

    char* ws = (char*)d_ws;
    size_t off = 0;
    auto take = [&](size_t bytes) { size_t r = off; off += (bytes + 255) & ~(size_t)255; return r; };
    int* counts   = (int*)(ws + take((size_t)N * 4));
    int* cursor   = (int*)(ws + take((size_t)N * 4));
    int* row_ptr  = (int*)(ws + take((size_t)(N + 1) * 4));
    int* bsums    = (int*)(ws + take(256 * 4));
    int* esrc     = (int*)(ws + take((size_t)E * 4));
    u16* W1t      = (u16*)(ws + take((size_t)128 * 1000 * 2));
    u16* Wct      = (u16*)(ws + take((size_t)128 * 256 * 2));
    u16* Wmt      = (u16*)(ws + take((size_t)32 * 128 * 2));
    u16* Wvt      = (u16*)(ws + take((size_t)32 * 128 * 2));
    float* ul2    = (float*)(ws + take(256 * 4));
    float* ur2    = (float*)(ws + take(256 * 4));
    float* bmean  = (float*)(ws + take(128 * 4));
    float* el1    = (float*)(ws + take((size_t)N * 4));
    float* er1    = (float*)(ws + take((size_t)N * 4));
    float* el2    = (float*)(ws + take((size_t)N * 2 * 4));
    float* er2    = (float*)(ws + take((size_t)N * 2 * 4));
    float* elm    = (float*)(ws + take((size_t)N * 2 * 4));
    float* erm    = (float*)(ws + take((size_t)N * 2 * 4));
    float* elv    = (float*)(ws + take((size_t)N * 2 * 4));
    float* erv    = (float*)(ws + take((size_t)N * 2 * 4));
    u16* o_bf     = (u16*)(ws + take((size_t)N * 128 * 2));
    u16* o2_bf    = (u16*)(ws + take((size_t)N * 128 * 2));
    u16* R        = (u16*)(ws + take((size_t)N * 256 * 2));
    u16* feat1    = R;          // layer-1 features [N,128]
    u16* agg      = R;          // layer-2 weighted aggregation of o [N,256] (after feat1 consumed)
    u16* featm    = R;          // mv features (after agg consumed)
    u16* featv    = R + (size_t)N * 32;
    (void)ws_size; (void)n_in; (void)in_sizes; (void)out_size;

    const int nb = (N + 255) / 256;
    const int eb = (E + 255) / 256;
    const int wb = (N + 3) / 4;
    const int gb = (N + 63) / 64;

    // CSR build
    k_zero<<<dim3(nb), 256, 0, stream>>>(counts, N);
    k_zero<<<dim3(nb), 256, 0, stream>>>(cursor, N);
    k_count<<<dim3(eb), 256, 0, stream>>>(dst, counts, E);
    k_scan1<<<dim3(nb), 256, 0, stream>>>(counts, row_ptr, bsums, N);
    k_scan2<<<dim3(1), 256, 0, stream>>>(bsums, nb);
    k_scan3<<<dim3(nb), 256, 0, stream>>>(row_ptr, bsums, N, E);
    k_fill<<<dim3(eb), 256, 0, stream>>>(src, dst, row_ptr, cursor, esrc, E);

    // weight prep
    k_transpose<<<dim3((1000 * 128 + 255) / 256), 256, 0, stream>>>(W1, W1t, 1000, 128);
    k_makeWc<<<dim3(128), 256, 0, stream>>>(W2, Wct);
    k_attnvec<<<dim3(1), 256, 0, stream>>>(W2, al2, ar2, b2, ul2, ur2, bmean);
    k_transpose<<<dim3((128 * 32 + 255) / 256), 256, 0, stream>>>(Wm, Wmt, 128, 32);
    k_transpose<<<dim3((128 * 32 + 255) / 256), 256, 0, stream>>>(Wv, Wvt, 128, 32);

    // layer 1 (A is f32)
    k_gemm_tiled<float, false><<<dim3(gb, 1), 256, 0, stream>>>(x, W1t, feat1, N, 128, 1000, nullptr, nullptr);
    k_eler1<<<dim3(wb), 256, 0, stream>>>(feat1, al1, ar1, el1, er1, N);
    k_agg1<<<dim3(wb), 256, 0, stream>>>(row_ptr, esrc, feat1, el1, er1, b1, o_bf, N);

    // layer 2: logits from o via folded vectors; aggregate o; project+bias+residual in GEMM epilogue
    k_eler2o<<<dim3(wb), 256, 0, stream>>>(o_bf, ul2, ur2, el2, er2, N);
    k_agg2o<<<dim3(wb), 256, 0, stream>>>(row_ptr, esrc, o_bf, el2, er2, agg, N);
    k_gemm_tiled<u16, true><<<dim3(gb, 1), 256, 0, stream>>>(agg, Wct, o2_bf, N, 128, 256, bmean, o_bf);

    // mean/var layers
    k_gemm<2><<<dim3(N / 16, 1), 64, 0, stream>>>(o2_bf, Wmt, featm, N, 32, 128);
    k_gemm<2><<<dim3(N / 16, 1), 64, 0, stream>>>(o2_bf, Wvt, featv, N, 32, 128);
    k_elermv<<<dim3(wb), 256, 0, stream>>>(featm, featv, alm, arm, alv, arv, elm, erm, elv, erv, N);
    k_aggmv<<<dim3(wb), 256, 0, stream>>>(row_ptr, esrc, featm, featv, elm, erm, elv, erv,
                                          bm, bv, eps, out, N);
}

// Round 2
// 650.715 us; speedup vs baseline: 1.0495x; 1.0423x over previous
//
#include <hip/hip_runtime.h>
#include <hip/hip_bf16.h>
#include <math.h>

typedef unsigned short u16;
typedef unsigned int u32;
typedef __attribute__((ext_vector_type(8))) __bf16 bf16x8;
typedef __attribute__((ext_vector_type(4))) float f32x4;
typedef __attribute__((ext_vector_type(4))) u32 u32x4;

#define NNODES 50000
#define NEDGES 800000

__device__ __forceinline__ float bf2f(u16 u) {
    union { u32 i; float f; } v; v.i = ((u32)u) << 16; return v.f;
}
__device__ __forceinline__ u16 f2bf(float x) {
    union { float f; u32 i; } v; v.f = x;
    u32 r = v.i + 0x7fffu + ((v.i >> 16) & 1u);
    return (u16)(r >> 16);
}
__device__ __forceinline__ float lrelu(float x) { return x >= 0.f ? x : 0.2f * x; }

// ---------------- CSR build ----------------
__global__ __launch_bounds__(256) void k_zero2(int* a, int* b, int count) {
    int i = blockIdx.x * 256 + threadIdx.x;
    if (i < count) { a[i] = 0; b[i] = 0; }
}

__global__ __launch_bounds__(256) void k_count(const int* __restrict__ dst, int* __restrict__ counts, int e) {
    int i = blockIdx.x * 256 + threadIdx.x;
    if (i < e) atomicAdd(&counts[dst[i]], 1);
}

__global__ __launch_bounds__(256) void k_scan1(const int* __restrict__ counts, int* __restrict__ row_ptr,
                                               int* __restrict__ bsums, int n) {
    __shared__ int tmp[256];
    int t = threadIdx.x, i = blockIdx.x * 256 + t;
    int v = (i < n) ? counts[i] : 0;
    tmp[t] = v; __syncthreads();
    for (int off = 1; off < 256; off <<= 1) {
        int x = 0; if (t >= off) x = tmp[t - off];
        __syncthreads(); tmp[t] += x; __syncthreads();
    }
    if (i < n) row_ptr[i] = tmp[t] - v;
    if (t == 255) bsums[blockIdx.x] = tmp[255];
}

__global__ __launch_bounds__(256) void k_scan2(int* bsums, int nb) {
    __shared__ int tmp[256];
    int t = threadIdx.x;
    int v = (t < nb) ? bsums[t] : 0;
    tmp[t] = v; __syncthreads();
    for (int off = 1; off < 256; off <<= 1) {
        int x = 0; if (t >= off) x = tmp[t - off];
        __syncthreads(); tmp[t] += x; __syncthreads();
    }
    if (t < nb) bsums[t] = tmp[t] - v;
}

__global__ __launch_bounds__(256) void k_scan3(int* __restrict__ row_ptr, const int* __restrict__ bsums,
                                               int n, int total) {
    int i = blockIdx.x * 256 + threadIdx.x;
    if (i < n) row_ptr[i] += bsums[blockIdx.x];
    if (i == 0) row_ptr[n] = total;
}

__global__ __launch_bounds__(256) void k_fill(const int* __restrict__ src, const int* __restrict__ dst,
                                              const int* __restrict__ row_ptr, int* __restrict__ cursor,
                                              int* __restrict__ esrc, int e) {
    int i = blockIdx.x * 256 + threadIdx.x;
    if (i < e) {
        int d = dst[i];
        int p = row_ptr[d] + atomicAdd(&cursor[d], 1);
        esrc[p] = src[i];
    }
}

// ---------------- fused weight prep ----------------
// blocks [0,500):   W1t[n*1000+k] = bf16(W1[k*128+n])           (1000x128 -> 128x1000)
// blocks [500,628): Wct[f*256+c]  = bf16(0.5*W2[k*256+h*128+f]) (head-mean combined, transposed)
// block 628:        ul/ur fold (al2/ar2 through W2) + bmean
// block 629:        Bmvt[c*128+k] = bf16(c<32 ? Wm[k*32+c] : Wv[k*32+c-32])
__global__ __launch_bounds__(256) void k_prep(const float* __restrict__ W1, const float* __restrict__ W2,
                                              const float* __restrict__ Wm, const float* __restrict__ Wv,
                                              const float* __restrict__ al2, const float* __restrict__ ar2,
                                              const float* __restrict__ b2,
                                              u16* __restrict__ W1t, u16* __restrict__ Wct,
                                              u16* __restrict__ Bmvt,
                                              float* __restrict__ ul, float* __restrict__ ur,
                                              float* __restrict__ bmean) {
    int b = blockIdx.x, t = threadIdx.x;
    if (b < 500) {
        int i = b * 256 + t;           // i < 128000
        int k = i >> 7, n = i & 127;
        W1t[(size_t)n * 1000 + k] = f2bf(W1[i]);
    } else if (b < 628) {
        int i = (b - 500) * 256 + t;   // i < 32768
        int f = i >> 8, c = i & 255, h = c >> 7, k = c & 127;
        Wct[i] = f2bf(0.5f * W2[(size_t)k * 256 + h * 128 + f]);
    } else if (b == 628) {
        int h = t >> 7, k = t & 127;
        const float* wrow = W2 + (size_t)k * 256 + h * 128;
        const float* alh = al2 + h * 128;
        const float* arh = ar2 + h * 128;
        float sl = 0.f, sr = 0.f;
        for (int f = 0; f < 128; f += 4) {
            f32x4 w = *(const f32x4*)(wrow + f);
            f32x4 a = *(const f32x4*)(alh + f);
            f32x4 r = *(const f32x4*)(arh + f);
#pragma unroll
            for (int q = 0; q < 4; q++) { sl += w[q] * a[q]; sr += w[q] * r[q]; }
        }
        ul[t] = sl; ur[t] = sr;
        if (t < 128) bmean[t] = 0.5f * (b2[t] + b2[128 + t]);
    } else {
        for (int i = t; i < 64 * 128; i += 256) {
            int c = i >> 7, k = i & 127;
            Bmvt[i] = f2bf(c < 32 ? Wm[(size_t)k * 32 + c] : Wv[(size_t)k * 32 + (c - 32)]);
        }
    }
}

// ---------------- A-fragment loaders (f32 or bf16 source) ----------------
__device__ __forceinline__ void load_af(const float* __restrict__ arow, int k0, int K, bf16x8& a) {
    if (k0 + 8 <= K) {
        f32x4 a0 = *(const f32x4*)(arow + k0);
        f32x4 a1 = *(const f32x4*)(arow + k0 + 4);
#pragma unroll
        for (int j = 0; j < 4; j++) { a[j] = (__bf16)a0[j]; a[4 + j] = (__bf16)a1[j]; }
    } else {
#pragma unroll
        for (int j = 0; j < 8; j++) a[j] = (__bf16)0.f;
    }
}
__device__ __forceinline__ void load_af(const u16* __restrict__ arow, int k0, int K, bf16x8& a) {
    if (k0 + 8 <= K) a = *(const bf16x8*)(arow + k0);
    else {
#pragma unroll
        for (int j = 0; j < 8; j++) a[j] = (__bf16)0.f;
    }
}

// ---------------- Tiled MFMA GEMM: C[M,Nn](bf16) = A[M,K] * Bt[Nn,K]^T ----------------
// MODE 0: layer-1 — also emit el[row] = sum_c C*al[c], er likewise (f32, pre-rounding)
// MODE 1: layer-2 — C = f2bf(acc + bias[col] + bf2f(resid[row*Nn+col]))
template <typename AT, int MODE>
__global__ __launch_bounds__(256) void k_gemm_tiled(const AT* __restrict__ A, const u16* __restrict__ Bt,
                                                    u16* __restrict__ C, int M, int Nn, int K,
                                                    const float* __restrict__ bias,
                                                    const u16* __restrict__ resid,
                                                    const float* __restrict__ al,
                                                    const float* __restrict__ ar,
                                                    float* __restrict__ el, float* __restrict__ er) {
    __shared__ __align__(16) u16 lb[2][128 * 40];
    const int tid = threadIdx.x;
    const int wave = tid >> 6, lane = tid & 63;
    const int m = lane & 15, quad = lane >> 4;
    const int row0 = blockIdx.x * 64 + wave * 16;
    const int col0 = blockIdx.y * 128;

    f32x4 acc[8];
#pragma unroll
    for (int t = 0; t < 8; t++)
#pragma unroll
        for (int r = 0; r < 4; r++) acc[t][r] = 0.f;

    int arr = row0 + m; if (arr > M - 1) arr = M - 1;  // clamp OOB rows (stores guarded)
    const AT* arow = A + (size_t)arr * K;
    const int scol = tid & 127;          // staging col
    const int sseg = (tid >> 7) * 16;    // staging k-base within tile (0 or 16)
    const u16* bcol = Bt + (size_t)(col0 + scol) * K;

    const int nsteps = (K + 31) >> 5;

#pragma unroll
    for (int p = 0; p < 2; ++p) {
        int kl = sseg + p * 8;
        u32x4 v = 0;
        if (kl < K) v = *(const u32x4*)(bcol + kl);
        *(u32x4*)&lb[0][scol * 40 + kl] = v;
    }
    bf16x8 acur, anext;
    load_af(arow, quad * 8, K, acur);
    __syncthreads();

    for (int s = 0; s < nsteps; ++s) {
        const int buf = s & 1;
        if (s + 1 < nsteps) {
            const int k0n = (s + 1) * 32;
            load_af(arow, k0n + quad * 8, K, anext);
#pragma unroll
            for (int p = 0; p < 2; ++p) {
                int kl = sseg + p * 8;
                u32x4 v = 0;
                if (k0n + kl < K) v = *(const u32x4*)(bcol + k0n + kl);
                *(u32x4*)&lb[buf ^ 1][scol * 40 + kl] = v;
            }
        }
#pragma unroll
        for (int t = 0; t < 8; ++t) {
            bf16x8 b = *(const bf16x8*)&lb[buf][(t * 16 + m) * 40 + quad * 8];
            acc[t] = __builtin_amdgcn_mfma_f32_16x16x32_bf16(acur, b, acc[t], 0, 0, 0);
        }
        acur = anext;
        __syncthreads();
    }

#pragma unroll
    for (int r = 0; r < 4; r++) {
        int row = row0 + quad * 4 + r;
        if (MODE == 0) {
            // attention-logit projections, full 128-wide row held across 16 m-lanes x 8 t
            float pe = 0.f, pr = 0.f;
#pragma unroll
            for (int t = 0; t < 8; t++) {
                float a = acc[t][r];
                int c = col0 + t * 16 + m;
                pe += a * al[c]; pr += a * ar[c];
            }
#pragma unroll
            for (int off = 8; off; off >>= 1) { pe += __shfl_xor(pe, off); pr += __shfl_xor(pr, off); }
            if (m == 0 && row < M) { el[row] = pe; er[row] = pr; }
        }
#pragma unroll
        for (int t = 0; t < 8; t++) {
            int col = col0 + t * 16 + m;
            if (row < M) {
                float v = acc[t][r];
                if (MODE == 1) v += bias[col] + bf2f(resid[(size_t)row * Nn + col]);
                C[(size_t)row * Nn + col] = f2bf(v);
            }
        }
    }
}

// ---------------- fused mean/var GEMM: [N,128] x [128,64] ([Wm|Wv] combined) ----------------
// Writes featm ([N,32], cols 0..31) and featv ([N,32], cols 32..63) and the four
// attention-logit projections elm/erm/elv/erv straight from f32 accumulators.
__global__ __launch_bounds__(64) void k_gemmmv(const u16* __restrict__ A, const u16* __restrict__ Bt,
                                               u16* __restrict__ featm, u16* __restrict__ featv,
                                               const float* __restrict__ alm, const float* __restrict__ arm,
                                               const float* __restrict__ alv, const float* __restrict__ arv,
                                               float* __restrict__ elm, float* __restrict__ erm,
                                               float* __restrict__ elv, float* __restrict__ erv, int M) {
    int row0 = blockIdx.x * 16;
    int lane = threadIdx.x;
    int m = lane & 15, quad = lane >> 4;
    f32x4 acc[4];
#pragma unroll
    for (int t = 0; t < 4; t++)
#pragma unroll
        for (int r = 0; r < 4; r++) acc[t][r] = 0.f;

    const u16* arow = A + (size_t)(row0 + m) * 128 + quad * 8;
#pragma unroll
    for (int s = 0; s < 4; ++s) {
        bf16x8 a = *(const bf16x8*)(arow + s * 32);
#pragma unroll
        for (int t = 0; t < 4; t++) {
            bf16x8 b = *(const bf16x8*)(Bt + (size_t)(t * 16 + m) * 128 + s * 32 + quad * 8);
            acc[t] = __builtin_amdgcn_mfma_f32_16x16x32_bf16(a, b, acc[t], 0, 0, 0);
        }
    }
#pragma unroll
    for (int r = 0; r < 4; r++) {
        int row = row0 + quad * 4 + r;
#pragma unroll
        for (int t = 0; t < 4; t++) {
            float a = acc[t][r];
            // logits: head h = t&1, table m/v = t>>1; feature idx within head = m
            const float* alp = (t < 2) ? alm : alv;
            const float* arp = (t < 2) ? arm : arv;
            float pe = a * alp[(t & 1) * 16 + m];
            float pr = a * arp[(t & 1) * 16 + m];
#pragma unroll
            for (int off = 8; off; off >>= 1) { pe += __shfl_xor(pe, off); pr += __shfl_xor(pr, off); }
            if (m == 0 && row < M) {
                float* elp = (t < 2) ? elm : elv;
                float* erp = (t < 2) ? erm : erv;
                elp[row * 2 + (t & 1)] = pe; erp[row * 2 + (t & 1)] = pr;
            }
            if (row < M) {
                u16 v = f2bf(a);
                if (t < 2) featm[(size_t)row * 32 + t * 16 + m] = v;
                else       featv[(size_t)row * 32 + (t - 2) * 16 + m] = v;
            }
        }
    }
}

// ---------------- aggregation: layer 1 (H=1,F=128) + fused layer-2 logit epilogue ----------------
__global__ __launch_bounds__(256) void k_agg1(const int* __restrict__ row_ptr, const int* __restrict__ esrc,
                                              const u16* __restrict__ feat, const float* __restrict__ el,
                                              const float* __restrict__ er, const float* __restrict__ bias,
                                              const float* __restrict__ ul, const float* __restrict__ ur,
                                              u16* __restrict__ o_bf, float* __restrict__ el2,
                                              float* __restrict__ er2, int n) {
    int node = blockIdx.x * 4 + (threadIdx.x >> 6);
    if (node >= n) return;
    int lane = threadIdx.x & 63;
    int beg = row_ptr[node], end = row_ptr[node + 1];
    float erd = er[node];
    float mx = -3.0e38f;
    for (int i = beg + lane; i < end; i += 64) mx = fmaxf(mx, el[esrc[i]]);
#pragma unroll
    for (int off = 32; off; off >>= 1) mx = fmaxf(mx, __shfl_xor(mx, off));
    float me = (end > beg) ? lrelu(mx + erd) : 0.f;
    float acc0 = 0.f, acc1 = 0.f, den = 0.f;
    for (int base = beg; base < end; base += 64) {
        int i = base + lane;
        float w = 0.f; int s = 0;
        if (i < end) { s = esrc[i]; w = expf(lrelu(el[s] + erd) - me); }
        den += w;
        int cnt = min(64, end - base);
        int j = 0;
        for (; j + 4 <= cnt; j += 4) {
            float w0 = __shfl(w, j), w1 = __shfl(w, j + 1), w2 = __shfl(w, j + 2), w3 = __shfl(w, j + 3);
            int s0 = __shfl(s, j), s1 = __shfl(s, j + 1), s2 = __shfl(s, j + 2), s3 = __shfl(s, j + 3);
            u32 p0 = ((const u32*)(feat + (size_t)s0 * 128))[lane];
            u32 p1 = ((const u32*)(feat + (size_t)s1 * 128))[lane];
            u32 p2 = ((const u32*)(feat + (size_t)s2 * 128))[lane];
            u32 p3 = ((const u32*)(feat + (size_t)s3 * 128))[lane];
            acc0 += w0 * bf2f((u16)(p0 & 0xffff)) + w1 * bf2f((u16)(p1 & 0xffff))
                  + w2 * bf2f((u16)(p2 & 0xffff)) + w3 * bf2f((u16)(p3 & 0xffff));
            acc1 += w0 * bf2f((u16)(p0 >> 16)) + w1 * bf2f((u16)(p1 >> 16))
                  + w2 * bf2f((u16)(p2 >> 16)) + w3 * bf2f((u16)(p3 >> 16));
        }
        for (; j < cnt; ++j) {
            float wj = __shfl(w, j);
            int sj = __shfl(s, j);
            u32 pv = ((const u32*)(feat + (size_t)sj * 128))[lane];
            acc0 += wj * bf2f((u16)(pv & 0xffff));
            acc1 += wj * bf2f((u16)(pv >> 16));
        }
    }
#pragma unroll
    for (int off = 32; off; off >>= 1) den += __shfl_xor(den, off);
    float inv = (den > 0.f) ? 1.f / den : 0.f;
    float o0 = acc0 * inv + bias[2 * lane];
    float o1 = acc1 * inv + bias[2 * lane + 1];
    // fused layer-2 attention logits from f32 o (removes the k_eler2o pass)
#pragma unroll
    for (int h = 0; h < 2; ++h) {
        float pe = o0 * ul[h * 128 + 2 * lane] + o1 * ul[h * 128 + 2 * lane + 1];
        float pr = o0 * ur[h * 128 + 2 * lane] + o1 * ur[h * 128 + 2 * lane + 1];
#pragma unroll
        for (int off = 32; off; off >>= 1) { pe += __shfl_xor(pe, off); pr += __shfl_xor(pr, off); }
        if (lane == 0) { el2[node * 2 + h] = pe; er2[node * 2 + h] = pr; }
    }
    u32 pv = (u32)f2bf(o0) | ((u32)f2bf(o1) << 16);
    ((u32*)(o_bf + (size_t)node * 128))[lane] = pv;
}

// ---------------- aggregation layer 2 over o (H=2 weights, 128-dim payload), 4-wide ----------------
__global__ __launch_bounds__(256) void k_agg2o(const int* __restrict__ row_ptr, const int* __restrict__ esrc,
                                               const u16* __restrict__ o_in, const float* __restrict__ el,
                                               const float* __restrict__ er, u16* __restrict__ agg, int n) {
    int node = blockIdx.x * 4 + (threadIdx.x >> 6);
    if (node >= n) return;
    int lane = threadIdx.x & 63;
    int beg = row_ptr[node], end = row_ptr[node + 1];
    float er0 = er[node * 2], er1 = er[node * 2 + 1];
    float mx0 = -3.0e38f, mx1 = -3.0e38f;
    for (int i = beg + lane; i < end; i += 64) {
        int s = esrc[i];
        float2 e2 = *(const float2*)(el + 2 * s);
        mx0 = fmaxf(mx0, e2.x); mx1 = fmaxf(mx1, e2.y);
    }
#pragma unroll
    for (int off = 32; off; off >>= 1) { mx0 = fmaxf(mx0, __shfl_xor(mx0, off)); mx1 = fmaxf(mx1, __shfl_xor(mx1, off)); }
    float me0 = (end > beg) ? lrelu(mx0 + er0) : 0.f;
    float me1 = (end > beg) ? lrelu(mx1 + er1) : 0.f;
    float a00 = 0.f, a01 = 0.f, a10 = 0.f, a11 = 0.f, d0 = 0.f, d1 = 0.f;
    for (int base = beg; base < end; base += 64) {
        int i = base + lane;
        float w0 = 0.f, w1 = 0.f; int s = 0;
        if (i < end) {
            s = esrc[i];
            float2 e2 = *(const float2*)(el + 2 * s);
            w0 = expf(lrelu(e2.x + er0) - me0);
            w1 = expf(lrelu(e2.y + er1) - me1);
        }
        d0 += w0; d1 += w1;
        int cnt = min(64, end - base);
        int j = 0;
        for (; j + 4 <= cnt; j += 4) {
            float w0a = __shfl(w0, j), w0b = __shfl(w0, j + 1), w0c = __shfl(w0, j + 2), w0d = __shfl(w0, j + 3);
            float w1a = __shfl(w1, j), w1b = __shfl(w1, j + 1), w1c = __shfl(w1, j + 2), w1d = __shfl(w1, j + 3);
            int sa = __shfl(s, j), sb = __shfl(s, j + 1), sc = __shfl(s, j + 2), sd = __shfl(s, j + 3);
            u32 pa = ((const u32*)(o_in + (size_t)sa * 128))[lane];
            u32 pb = ((const u32*)(o_in + (size_t)sb * 128))[lane];
            u32 pc = ((const u32*)(o_in + (size_t)sc * 128))[lane];
            u32 pd = ((const u32*)(o_in + (size_t)sd * 128))[lane];
            float la = bf2f((u16)(pa & 0xffff)), ha = bf2f((u16)(pa >> 16));
            float lb = bf2f((u16)(pb & 0xffff)), hb = bf2f((u16)(pb >> 16));
            float lc = bf2f((u16)(pc & 0xffff)), hc = bf2f((u16)(pc >> 16));
            float ld = bf2f((u16)(pd & 0xffff)), hd = bf2f((u16)(pd >> 16));
            a00 += w0a * la + w0b * lb + w0c * lc + w0d * ld;
            a01 += w0a * ha + w0b * hb + w0c * hc + w0d * hd;
            a10 += w1a * la + w1b * lb + w1c * lc + w1d * ld;
            a11 += w1a * ha + w1b * hb + w1c * hc + w1d * hd;
        }
        for (; j < cnt; ++j) {
            float w0j = __shfl(w0, j), w1j = __shfl(w1, j);
            int sj = __shfl(s, j);
            u32 pv = ((const u32*)(o_in + (size_t)sj * 128))[lane];
            float lo = bf2f((u16)(pv & 0xffff)), hi = bf2f((u16)(pv >> 16));
            a00 += w0j * lo; a01 += w0j * hi;
            a10 += w1j * lo; a11 += w1j * hi;
        }
    }
#pragma unroll
    for (int off = 32; off; off >>= 1) { d0 += __shfl_xor(d0, off); d1 += __shfl_xor(d1, off); }
    float i0 = (d0 > 0.f) ? 1.f / d0 : 0.f, i1 = (d1 > 0.f) ? 1.f / d1 : 0.f;
    u32 p0 = (u32)f2bf(a00 * i0) | ((u32)f2bf(a01 * i0) << 16);
    u32 p1 = (u32)f2bf(a10 * i1) | ((u32)f2bf(a11 * i1) << 16);
    u32* aw = (u32*)(agg + (size_t)node * 256);
    aw[lane] = p0;
    aw[64 + lane] = p1;
}

// ---------------- aggregation: mean & var fused (H=2,F=16), edge-parallel + reparameterize ----------------
__global__ __launch_bounds__(256) void k_aggmv(const int* __restrict__ row_ptr, const int* __restrict__ esrc,
                                               const u16* __restrict__ featm, const u16* __restrict__ featv,
                                               const float* __restrict__ elm, const float* __restrict__ erm,
                                               const float* __restrict__ elv, const float* __restrict__ erv,
                                               const float* __restrict__ bm, const float* __restrict__ bv,
                                               const float* __restrict__ eps, float* __restrict__ out, int n) {
    int node = blockIdx.x * 4 + (threadIdx.x >> 6);
    if (node >= n) return;
    int lane = threadIdx.x & 63;
    int f = lane & 15, h = (lane >> 4) & 1, tbl = lane >> 5;
    int beg = row_ptr[node], end = row_ptr[node + 1];
    float erm0 = erm[2 * node], erm1 = erm[2 * node + 1];
    float erv0 = erv[2 * node], erv1 = erv[2 * node + 1];
    float mm0 = -3.0e38f, mm1 = -3.0e38f, mv0 = -3.0e38f, mv1 = -3.0e38f;
    for (int i = beg + lane; i < end; i += 64) {
        int s = esrc[i];
        float2 em = *(const float2*)(elm + 2 * s);
        float2 ev = *(const float2*)(elv + 2 * s);
        mm0 = fmaxf(mm0, em.x); mm1 = fmaxf(mm1, em.y);
        mv0 = fmaxf(mv0, ev.x); mv1 = fmaxf(mv1, ev.y);
    }
#pragma unroll
    for (int off = 32; off; off >>= 1) {
        mm0 = fmaxf(mm0, __shfl_xor(mm0, off)); mm1 = fmaxf(mm1, __shfl_xor(mm1, off));
        mv0 = fmaxf(mv0, __shfl_xor(mv0, off)); mv1 = fmaxf(mv1, __shfl_xor(mv1, off));
    }
    float mem0 = (end > beg) ? lrelu(mm0 + erm0) : 0.f;
    float mem1 = (end > beg) ? lrelu(mm1 + erm1) : 0.f;
    float mev0 = (end > beg) ? lrelu(mv0 + erv0) : 0.f;
    float mev1 = (end > beg) ? lrelu(mv1 + erv1) : 0.f;

    const u16* ftp = tbl ? featv : featm;
    const int fidx = h * 16 + f;
    float accv = 0.f;
    float dm0 = 0.f, dm1 = 0.f, dv0 = 0.f, dv1 = 0.f;
    for (int base = beg; base < end; base += 64) {
        int i = base + lane;
        float wm0 = 0.f, wm1 = 0.f, wv0 = 0.f, wv1 = 0.f; int s = 0;
        if (i < end) {
            s = esrc[i];
            float2 em = *(const float2*)(elm + 2 * s);
            float2 ev = *(const float2*)(elv + 2 * s);
            wm0 = expf(lrelu(em.x + erm0) - mem0);
            wm1 = expf(lrelu(em.y + erm1) - mem1);
            wv0 = expf(lrelu(ev.x + erv0) - mev0);
            wv1 = expf(lrelu(ev.y + erv1) - mev1);
        }
        dm0 += wm0; dm1 += wm1; dv0 += wv0; dv1 += wv1;
        int cnt = min(64, end - base);
        for (int j = 0; j < cnt; ++j) {
            int sj = __shfl(s, j);
            float bm0 = __shfl(wm0, j);   // unconditional broadcasts (converged)
            float bm1 = __shfl(wm1, j);
            float bv0 = __shfl(wv0, j);
            float bv1 = __shfl(wv1, j);
            float wj = tbl ? (h ? bv1 : bv0) : (h ? bm1 : bm0);  // local select, safe
            accv += wj * bf2f(ftp[(size_t)sj * 32 + fidx]);
        }
    }
#pragma unroll
    for (int off = 32; off; off >>= 1) {
        dm0 += __shfl_xor(dm0, off); dm1 += __shfl_xor(dm1, off);
        dv0 += __shfl_xor(dv0, off); dv1 += __shfl_xor(dv1, off);
    }
    float den = tbl ? (h ? dv1 : dv0) : (h ? dm1 : dm0);
    float inv = (den > 0.f) ? 1.f / den : 0.f;
    float biasc = tbl ? bv[fidx] : bm[fidx];
    float outc = accv * inv + biasc;
    float hm = 0.5f * (outc + __shfl_xor(outc, 16));  // mean over the 2 heads (same tbl)
    float meanv = __shfl(hm, f);                      // tbl=0 lane
    float varp = __shfl(hm, 32 + f);                  // tbl=1 lane
    if (lane < 16) {
        float var = expf(varp);
        float z = meanv + sqrtf(var) * eps[(size_t)node * 16 + f];
        size_t base = (size_t)node * 16 + f;
        out[base] = z;
        out[(size_t)NNODES * 16 + base] = meanv;
        out[(size_t)2 * NNODES * 16 + base] = var;
    }
}

// ---------------- host ----------------
extern "C" void kernel_launch(void* const* d_in, const int* in_sizes, int n_in,
                              void* d_out, int out_size, void* d_ws, size_t ws_size,
                              hipStream_t stream) {
    const int N = NNODES, E = NEDGES;
    const float* x   = (const float*)d_in[0];
    const int* src   = (const int*)d_in[1];
    const int* dst   = (const int*)d_in[2];
    const float* W1  = (const float*)d_in[3];
    const float* al1 = (const float*)d_in[4];
    const float* ar1 = (const float*)d_in[5];
    const float* b1  = (const float*)d_in[6];
    const float* W2  = (const float*)d_in[7];
    const float* al2 = (const float*)d_in[8];
    const float* ar2 = (const float*)d_in[9];
    const float* b2  = (const float*)d_in[10];
    const float* Wm  = (const float*)d_in[11];
    const float* alm = (const float*)d_in[12];
    const float* arm = (const float*)d_in[13];
    const float* bm  = (const float*)d_in[14];
    const float* Wv  = (const float*)d_in[15];
    const float* alv = (const float*)d_in[16];
    const float* arv = (const float*)d_in[17];
    const float* bv  = (const float*)d_in[18];
    const float* eps = (const float*)d_in[19];
    float* out = (float*)d_out;

    char* ws = (char*)d_ws;
    size_t off = 0;
    auto take = [&](size_t bytes) { size_t r = off; off += (bytes + 255) & ~(size_t)255; return r; };
    int* counts   = (int*)(ws + take((size_t)N * 4));
    int* cursor   = (int*)(ws + take((size_t)N * 4));
    int* row_ptr  = (int*)(ws + take((size_t)(N + 1) * 4));
    int* bsums    = (int*)(ws + take(256 * 4));
    int* esrc     = (int*)(ws + take((size_t)E * 4));
    u16* W1t      = (u16*)(ws + take((size_t)128 * 1000 * 2));
    u16* Wct      = (u16*)(ws + take((size_t)128 * 256 * 2));
    u16* Bmvt     = (u16*)(ws + take((size_t)64 * 128 * 2));
    float* ul2    = (float*)(ws + take(256 * 4));
    float* ur2    = (float*)(ws + take(256 * 4));
    float* bmean  = (float*)(ws + take(128 * 4));
    float* el1    = (float*)(ws + take((size_t)N * 4));
    float* er1    = (float*)(ws + take((size_t)N * 4));
    float* el2    = (float*)(ws + take((size_t)N * 2 * 4));
    float* er2    = (float*)(ws + take((size_t)N * 2 * 4));
    float* elm    = (float*)(ws + take((size_t)N * 2 * 4));
    float* erm    = (float*)(ws + take((size_t)N * 2 * 4));
    float* elv    = (float*)(ws + take((size_t)N * 2 * 4));
    float* erv    = (float*)(ws + take((size_t)N * 2 * 4));
    u16* o_bf     = (u16*)(ws + take((size_t)N * 128 * 2));
    u16* o2_bf    = (u16*)(ws + take((size_t)N * 128 * 2));
    u16* R        = (u16*)(ws + take((size_t)N * 256 * 2));
    u16* feat1    = R;          // layer-1 features [N,128]
    u16* agg      = R;          // layer-2 weighted aggregation of o [N,256] (after feat1 consumed)
    u16* featm    = R;          // mv features (after agg consumed)
    u16* featv    = R + (size_t)N * 32;
    (void)ws_size; (void)n_in; (void)in_sizes; (void)out_size;

    const int nb = (N + 255) / 256;
    const int eb = (E + 255) / 256;
    const int wb = (N + 3) / 4;
    const int gb = (N + 63) / 64;

    // fused weight prep (independent of CSR)
    k_prep<<<dim3(630), 256, 0, stream>>>(W1, W2, Wm, Wv, al2, ar2, b2, W1t, Wct, Bmvt, ul2, ur2, bmean);

    // CSR build
    k_zero2<<<dim3(nb), 256, 0, stream>>>(counts, cursor, N);
    k_count<<<dim3(eb), 256, 0, stream>>>(dst, counts, E);
    k_scan1<<<dim3(nb), 256, 0, stream>>>(counts, row_ptr, bsums, N);
    k_scan2<<<dim3(1), 256, 0, stream>>>(bsums, nb);
    k_scan3<<<dim3(nb), 256, 0, stream>>>(row_ptr, bsums, N, E);
    k_fill<<<dim3(eb), 256, 0, stream>>>(src, dst, row_ptr, cursor, esrc, E);

    // layer 1 (A is f32): GEMM + fused el1/er1
    k_gemm_tiled<float, 0><<<dim3(gb, 1), 256, 0, stream>>>(x, W1t, feat1, N, 128, 1000,
                                                            nullptr, nullptr, al1, ar1, el1, er1);
    k_agg1<<<dim3(wb), 256, 0, stream>>>(row_ptr, esrc, feat1, el1, er1, b1, ul2, ur2,
                                         o_bf, el2, er2, N);

    // layer 2: aggregate o; project+bias+residual in GEMM epilogue
    k_agg2o<<<dim3(wb), 256, 0, stream>>>(row_ptr, esrc, o_bf, el2, er2, agg, N);
    k_gemm_tiled<u16, 1><<<dim3(gb, 1), 256, 0, stream>>>(agg, Wct, o2_bf, N, 128, 256,
                                                          bmean, o_bf, nullptr, nullptr, nullptr, nullptr);

    // mean/var: single fused GEMM (m|v) + fused logits
    k_gemmmv<<<dim3(N / 16), 64, 0, stream>>>(o2_bf, Bmvt, featm, featv, alm, arm, alv, arv,
                                              elm, erm, elv, erv, N);
    k_aggmv<<<dim3(wb), 256, 0, stream>>>(row_ptr, esrc, featm, featv, elm, erm, elv, erv,
                                          bm, bv, eps, out, N);
}

// Round 3
// 577.278 us; speedup vs baseline: 1.1830x; 1.1272x over previous
//
#include <hip/hip_runtime.h>
#include <hip/hip_bf16.h>
#include <math.h>

typedef unsigned short u16;
typedef unsigned int u32;
typedef __attribute__((ext_vector_type(8))) __bf16 bf16x8;
typedef __attribute__((ext_vector_type(4))) float f32x4;
typedef __attribute__((ext_vector_type(4))) u32 u32x4;
typedef __attribute__((ext_vector_type(2))) u32 u32x2;

#define NNODES 50000
#define NEDGES 800000

__device__ __forceinline__ float bf2f(u16 u) {
    union { u32 i; float f; } v; v.i = ((u32)u) << 16; return v.f;
}
__device__ __forceinline__ u16 f2bf(float x) {
    union { float f; u32 i; } v; v.f = x;
    u32 r = v.i + 0x7fffu + ((v.i >> 16) & 1u);
    return (u16)(r >> 16);
}
__device__ __forceinline__ float lrelu(float x) { return x >= 0.f ? x : 0.2f * x; }

// ---------------- CSR build ----------------
__global__ __launch_bounds__(256) void k_zero2(int* a, int* b, int count) {
    int i = blockIdx.x * 256 + threadIdx.x;
    if (i < count) { a[i] = 0; b[i] = 0; }
}

__global__ __launch_bounds__(256) void k_count(const int* __restrict__ dst, int* __restrict__ counts, int e) {
    int i = blockIdx.x * 256 + threadIdx.x;
    if (i < e) atomicAdd(&counts[dst[i]], 1);
}

__global__ __launch_bounds__(256) void k_scan1(const int* __restrict__ counts, int* __restrict__ row_ptr,
                                               int* __restrict__ bsums, int n) {
    __shared__ int tmp[256];
    int t = threadIdx.x, i = blockIdx.x * 256 + t;
    int v = (i < n) ? counts[i] : 0;
    tmp[t] = v; __syncthreads();
    for (int off = 1; off < 256; off <<= 1) {
        int x = 0; if (t >= off) x = tmp[t - off];
        __syncthreads(); tmp[t] += x; __syncthreads();
    }
    if (i < n) row_ptr[i] = tmp[t] - v;
    if (t == 255) bsums[blockIdx.x] = tmp[255];
}

__global__ __launch_bounds__(256) void k_scan2(int* bsums, int nb) {
    __shared__ int tmp[256];
    int t = threadIdx.x;
    int v = (t < nb) ? bsums[t] : 0;
    tmp[t] = v; __syncthreads();
    for (int off = 1; off < 256; off <<= 1) {
        int x = 0; if (t >= off) x = tmp[t - off];
        __syncthreads(); tmp[t] += x; __syncthreads();
    }
    if (t < nb) bsums[t] = tmp[t] - v;
}

__global__ __launch_bounds__(256) void k_scan3(int* __restrict__ row_ptr, const int* __restrict__ bsums,
                                               int n, int total) {
    int i = blockIdx.x * 256 + threadIdx.x;
    if (i < n) row_ptr[i] += bsums[blockIdx.x];
    if (i == 0) row_ptr[n] = total;
}

__global__ __launch_bounds__(256) void k_fill(const int* __restrict__ src, const int* __restrict__ dst,
                                              const int* __restrict__ row_ptr, int* __restrict__ cursor,
                                              int* __restrict__ esrc, int e) {
    int i = blockIdx.x * 256 + threadIdx.x;
    if (i < e) {
        int d = dst[i];
        int p = row_ptr[d] + atomicAdd(&cursor[d], 1);
        esrc[p] = src[i];
    }
}

// ---------------- fused weight prep ----------------
__global__ __launch_bounds__(256) void k_prep(const float* __restrict__ W1, const float* __restrict__ W2,
                                              const float* __restrict__ Wm, const float* __restrict__ Wv,
                                              const float* __restrict__ al2, const float* __restrict__ ar2,
                                              const float* __restrict__ b2,
                                              u16* __restrict__ W1t, u16* __restrict__ Wct,
                                              u16* __restrict__ Bmvt,
                                              float* __restrict__ ul, float* __restrict__ ur,
                                              float* __restrict__ bmean) {
    int b = blockIdx.x, t = threadIdx.x;
    if (b < 500) {
        int i = b * 256 + t;           // i < 128000
        int k = i >> 7, n = i & 127;
        W1t[(size_t)n * 1000 + k] = f2bf(W1[i]);
    } else if (b < 628) {
        int i = (b - 500) * 256 + t;   // i < 32768
        int f = i >> 8, c = i & 255, h = c >> 7, k = c & 127;
        Wct[i] = f2bf(0.5f * W2[(size_t)k * 256 + h * 128 + f]);
    } else if (b == 628) {
        int h = t >> 7, k = t & 127;
        const float* wrow = W2 + (size_t)k * 256 + h * 128;
        const float* alh = al2 + h * 128;
        const float* arh = ar2 + h * 128;
        float sl = 0.f, sr = 0.f;
        for (int f = 0; f < 128; f += 4) {
            f32x4 w = *(const f32x4*)(wrow + f);
            f32x4 a = *(const f32x4*)(alh + f);
            f32x4 r = *(const f32x4*)(arh + f);
#pragma unroll
            for (int q = 0; q < 4; q++) { sl += w[q] * a[q]; sr += w[q] * r[q]; }
        }
        ul[t] = sl; ur[t] = sr;
        if (t < 128) bmean[t] = 0.5f * (b2[t] + b2[128 + t]);
    } else {
        for (int i = t; i < 64 * 128; i += 256) {
            int c = i >> 7, k = i & 127;
            Bmvt[i] = f2bf(c < 32 ? Wm[(size_t)k * 32 + c] : Wv[(size_t)k * 32 + (c - 32)]);
        }
    }
}

// ---------------- A-fragment loaders (f32 or bf16 source) ----------------
__device__ __forceinline__ void load_af(const float* __restrict__ arow, int k0, int K, bf16x8& a) {
    if (k0 + 8 <= K) {
        f32x4 a0 = *(const f32x4*)(arow + k0);
        f32x4 a1 = *(const f32x4*)(arow + k0 + 4);
#pragma unroll
        for (int j = 0; j < 4; j++) { a[j] = (__bf16)a0[j]; a[4 + j] = (__bf16)a1[j]; }
    } else {
#pragma unroll
        for (int j = 0; j < 8; j++) a[j] = (__bf16)0.f;
    }
}
__device__ __forceinline__ void load_af(const u16* __restrict__ arow, int k0, int K, bf16x8& a) {
    if (k0 + 8 <= K) a = *(const bf16x8*)(arow + k0);
    else {
#pragma unroll
        for (int j = 0; j < 8; j++) a[j] = (__bf16)0.f;
    }
}

// ---------------- Tiled MFMA GEMM: C[M,Nn](bf16) = A[M,K] * Bt[Nn,K]^T ----------------
// MODE 0: layer-1 — also emit el[row] = sum_c C*al[c], er likewise (f32, pre-rounding)
// MODE 1: layer-2 — C = f2bf(acc + bias[col] + bf2f(resid[row*Nn+col]))
template <typename AT, int MODE>
__global__ __launch_bounds__(256) void k_gemm_tiled(const AT* __restrict__ A, const u16* __restrict__ Bt,
                                                    u16* __restrict__ C, int M, int Nn, int K,
                                                    const float* __restrict__ bias,
                                                    const u16* __restrict__ resid,
                                                    const float* __restrict__ al,
                                                    const float* __restrict__ ar,
                                                    float* __restrict__ el, float* __restrict__ er) {
    __shared__ __align__(16) u16 lb[2][128 * 40];
    const int tid = threadIdx.x;
    const int wave = tid >> 6, lane = tid & 63;
    const int m = lane & 15, quad = lane >> 4;
    const int row0 = blockIdx.x * 64 + wave * 16;
    const int col0 = blockIdx.y * 128;

    f32x4 acc[8];
#pragma unroll
    for (int t = 0; t < 8; t++)
#pragma unroll
        for (int r = 0; r < 4; r++) acc[t][r] = 0.f;

    int arr = row0 + m; if (arr > M - 1) arr = M - 1;  // clamp OOB rows (stores guarded)
    const AT* arow = A + (size_t)arr * K;
    const int scol = tid & 127;          // staging col
    const int sseg = (tid >> 7) * 16;    // staging k-base within tile (0 or 16)
    const u16* bcol = Bt + (size_t)(col0 + scol) * K;

    const int nsteps = (K + 31) >> 5;

#pragma unroll
    for (int p = 0; p < 2; ++p) {
        int kl = sseg + p * 8;
        u32x4 v = 0;
        if (kl < K) v = *(const u32x4*)(bcol + kl);
        *(u32x4*)&lb[0][scol * 40 + kl] = v;
    }
    bf16x8 acur, anext;
    load_af(arow, quad * 8, K, acur);
    __syncthreads();

    for (int s = 0; s < nsteps; ++s) {
        const int buf = s & 1;
        if (s + 1 < nsteps) {
            const int k0n = (s + 1) * 32;
            load_af(arow, k0n + quad * 8, K, anext);
#pragma unroll
            for (int p = 0; p < 2; ++p) {
                int kl = sseg + p * 8;
                u32x4 v = 0;
                if (k0n + kl < K) v = *(const u32x4*)(bcol + k0n + kl);
                *(u32x4*)&lb[buf ^ 1][scol * 40 + kl] = v;
            }
        }
#pragma unroll
        for (int t = 0; t < 8; ++t) {
            bf16x8 b = *(const bf16x8*)&lb[buf][(t * 16 + m) * 40 + quad * 8];
            acc[t] = __builtin_amdgcn_mfma_f32_16x16x32_bf16(acur, b, acc[t], 0, 0, 0);
        }
        acur = anext;
        __syncthreads();
    }

#pragma unroll
    for (int r = 0; r < 4; r++) {
        int row = row0 + quad * 4 + r;
        if (MODE == 0) {
            float pe = 0.f, pr = 0.f;
#pragma unroll
            for (int t = 0; t < 8; t++) {
                float a = acc[t][r];
                int c = col0 + t * 16 + m;
                pe += a * al[c]; pr += a * ar[c];
            }
#pragma unroll
            for (int off = 8; off; off >>= 1) { pe += __shfl_xor(pe, off); pr += __shfl_xor(pr, off); }
            if (m == 0 && row < M) { el[row] = pe; er[row] = pr; }
        }
#pragma unroll
        for (int t = 0; t < 8; t++) {
            int col = col0 + t * 16 + m;
            if (row < M) {
                float v = acc[t][r];
                if (MODE == 1) v += bias[col] + bf2f(resid[(size_t)row * Nn + col]);
                C[(size_t)row * Nn + col] = f2bf(v);
            }
        }
    }
}

// ---------------- fused mean/var GEMM: [N,128] x [128,64] ([Wm|Wv] combined) ----------------
// Writes INTERLEAVED featmv [N,64] (cols 0..31 = m, 32..63 = v) + the four attention-logit
// projections elm/erm/elv/erv straight from f32 accumulators.
__global__ __launch_bounds__(64) void k_gemmmv(const u16* __restrict__ A, const u16* __restrict__ Bt,
                                               u16* __restrict__ featmv,
                                               const float* __restrict__ alm, const float* __restrict__ arm,
                                               const float* __restrict__ alv, const float* __restrict__ arv,
                                               float* __restrict__ elm, float* __restrict__ erm,
                                               float* __restrict__ elv, float* __restrict__ erv, int M) {
    int row0 = blockIdx.x * 16;
    int lane = threadIdx.x;
    int m = lane & 15, quad = lane >> 4;
    f32x4 acc[4];
#pragma unroll
    for (int t = 0; t < 4; t++)
#pragma unroll
        for (int r = 0; r < 4; r++) acc[t][r] = 0.f;

    const u16* arow = A + (size_t)(row0 + m) * 128 + quad * 8;
#pragma unroll
    for (int s = 0; s < 4; ++s) {
        bf16x8 a = *(const bf16x8*)(arow + s * 32);
#pragma unroll
        for (int t = 0; t < 4; t++) {
            bf16x8 b = *(const bf16x8*)(Bt + (size_t)(t * 16 + m) * 128 + s * 32 + quad * 8);
            acc[t] = __builtin_amdgcn_mfma_f32_16x16x32_bf16(a, b, acc[t], 0, 0, 0);
        }
    }
#pragma unroll
    for (int r = 0; r < 4; r++) {
        int row = row0 + quad * 4 + r;
#pragma unroll
        for (int t = 0; t < 4; t++) {
            float a = acc[t][r];
            const float* alp = (t < 2) ? alm : alv;
            const float* arp = (t < 2) ? arm : arv;
            float pe = a * alp[(t & 1) * 16 + m];
            float pr = a * arp[(t & 1) * 16 + m];
#pragma unroll
            for (int off = 8; off; off >>= 1) { pe += __shfl_xor(pe, off); pr += __shfl_xor(pr, off); }
            if (m == 0 && row < M) {
                float* elp = (t < 2) ? elm : elv;
                float* erp = (t < 2) ? erm : erv;
                elp[row * 2 + (t & 1)] = pe; erp[row * 2 + (t & 1)] = pr;
            }
            if (row < M) featmv[(size_t)row * 64 + t * 16 + m] = f2bf(a);
        }
    }
}

// ---------------- aggregation: layer 1 (H=1,F=128), 2 nodes/wave, single-pass softmax ----------------
// half = lane>>5 owns one node; 32 lanes x u32x2 cover the 128-wide payload row.
// Lanes past a half's degree carry w=0/s=0, so cross-half imbalance is benign.
__global__ __launch_bounds__(256) void k_agg1(const int* __restrict__ row_ptr, const int* __restrict__ esrc,
                                              const u16* __restrict__ feat, const float* __restrict__ el,
                                              const float* __restrict__ er, const float* __restrict__ bias,
                                              const float* __restrict__ ul, const float* __restrict__ ur,
                                              u16* __restrict__ o_bf, float* __restrict__ el2,
                                              float* __restrict__ er2, int n) {
    int wave = threadIdx.x >> 6, lane = threadIdx.x & 63;
    int l = lane & 31;
    int node = blockIdx.x * 8 + wave * 2 + (lane >> 5);
    if (node >= n) node = n - 1;               // N%8==0: never taken, keeps shfl convergent
    int beg = row_ptr[node], deg = row_ptr[node + 1] - beg;
    float erd = er[node];
    int degmax = max(deg, __shfl_xor(deg, 32));
    const int srcb = lane & 32;
    float acc0 = 0.f, acc1 = 0.f, acc2 = 0.f, acc3 = 0.f, den = 0.f;
    for (int off0 = 0; off0 < degmax; off0 += 32) {
        float w = 0.f; int s = 0;
        if (off0 + l < deg) { s = esrc[beg + off0 + l]; w = expf(lrelu(el[s] + erd)); }
        den += w;
        int cnt = min(32, degmax - off0);
        int j = 0;
        for (; j + 4 <= cnt; j += 4) {
            int s0 = __shfl(s, srcb + j),     s1 = __shfl(s, srcb + j + 1);
            int s2 = __shfl(s, srcb + j + 2), s3 = __shfl(s, srcb + j + 3);
            float w0 = __shfl(w, srcb + j),     w1 = __shfl(w, srcb + j + 1);
            float w2 = __shfl(w, srcb + j + 2), w3 = __shfl(w, srcb + j + 3);
            u32x2 p0 = ((const u32x2*)(feat + (size_t)s0 * 128))[l];
            u32x2 p1 = ((const u32x2*)(feat + (size_t)s1 * 128))[l];
            u32x2 p2 = ((const u32x2*)(feat + (size_t)s2 * 128))[l];
            u32x2 p3 = ((const u32x2*)(feat + (size_t)s3 * 128))[l];
            acc0 += w0 * bf2f((u16)(p0.x & 0xffff)) + w1 * bf2f((u16)(p1.x & 0xffff))
                  + w2 * bf2f((u16)(p2.x & 0xffff)) + w3 * bf2f((u16)(p3.x & 0xffff));
            acc1 += w0 * bf2f((u16)(p0.x >> 16)) + w1 * bf2f((u16)(p1.x >> 16))
                  + w2 * bf2f((u16)(p2.x >> 16)) + w3 * bf2f((u16)(p3.x >> 16));
            acc2 += w0 * bf2f((u16)(p0.y & 0xffff)) + w1 * bf2f((u16)(p1.y & 0xffff))
                  + w2 * bf2f((u16)(p2.y & 0xffff)) + w3 * bf2f((u16)(p3.y & 0xffff));
            acc3 += w0 * bf2f((u16)(p0.y >> 16)) + w1 * bf2f((u16)(p1.y >> 16))
                  + w2 * bf2f((u16)(p2.y >> 16)) + w3 * bf2f((u16)(p3.y >> 16));
        }
        for (; j < cnt; ++j) {
            int sj = __shfl(s, srcb + j);
            float wj = __shfl(w, srcb + j);
            u32x2 pv = ((const u32x2*)(feat + (size_t)sj * 128))[l];
            acc0 += wj * bf2f((u16)(pv.x & 0xffff));
            acc1 += wj * bf2f((u16)(pv.x >> 16));
            acc2 += wj * bf2f((u16)(pv.y & 0xffff));
            acc3 += wj * bf2f((u16)(pv.y >> 16));
        }
    }
#pragma unroll
    for (int off = 16; off; off >>= 1) den += __shfl_xor(den, off);
    float inv = (den > 0.f) ? 1.f / den : 0.f;
    const int c0 = 4 * l;
    float o0 = acc0 * inv + bias[c0];
    float o1 = acc1 * inv + bias[c0 + 1];
    float o2 = acc2 * inv + bias[c0 + 2];
    float o3 = acc3 * inv + bias[c0 + 3];
    // fused layer-2 attention logits from f32 o
#pragma unroll
    for (int h = 0; h < 2; ++h) {
        const float* ulh = ul + h * 128 + c0;
        const float* urh = ur + h * 128 + c0;
        float pe = o0 * ulh[0] + o1 * ulh[1] + o2 * ulh[2] + o3 * ulh[3];
        float pr = o0 * urh[0] + o1 * urh[1] + o2 * urh[2] + o3 * urh[3];
#pragma unroll
        for (int off = 16; off; off >>= 1) { pe += __shfl_xor(pe, off); pr += __shfl_xor(pr, off); }
        if (l == 0) { el2[node * 2 + h] = pe; er2[node * 2 + h] = pr; }
    }
    u32x2 pv;
    pv.x = (u32)f2bf(o0) | ((u32)f2bf(o1) << 16);
    pv.y = (u32)f2bf(o2) | ((u32)f2bf(o3) << 16);
    ((u32x2*)(o_bf + (size_t)node * 128))[l] = pv;
}

// ---------------- aggregation layer 2 over o (H=2 weights, 128-dim payload), 2 nodes/wave ----------------
__global__ __launch_bounds__(256) void k_agg2o(const int* __restrict__ row_ptr, const int* __restrict__ esrc,
                                               const u16* __restrict__ o_in, const float* __restrict__ el,
                                               const float* __restrict__ er, u16* __restrict__ agg, int n) {
    int wave = threadIdx.x >> 6, lane = threadIdx.x & 63;
    int l = lane & 31;
    int node = blockIdx.x * 8 + wave * 2 + (lane >> 5);
    if (node >= n) node = n - 1;
    int beg = row_ptr[node], deg = row_ptr[node + 1] - beg;
    float er0 = er[node * 2], er1 = er[node * 2 + 1];
    int degmax = max(deg, __shfl_xor(deg, 32));
    const int srcb = lane & 32;
    float a00 = 0.f, a01 = 0.f, a02 = 0.f, a03 = 0.f;
    float a10 = 0.f, a11 = 0.f, a12 = 0.f, a13 = 0.f;
    float d0 = 0.f, d1 = 0.f;
    for (int off0 = 0; off0 < degmax; off0 += 32) {
        float w0 = 0.f, w1 = 0.f; int s = 0;
        if (off0 + l < deg) {
            s = esrc[beg + off0 + l];
            float2 e2 = *(const float2*)(el + 2 * s);
            w0 = expf(lrelu(e2.x + er0));
            w1 = expf(lrelu(e2.y + er1));
        }
        d0 += w0; d1 += w1;
        int cnt = min(32, degmax - off0);
        int j = 0;
        for (; j + 2 <= cnt; j += 2) {
            int sa = __shfl(s, srcb + j), sb = __shfl(s, srcb + j + 1);
            float w0a = __shfl(w0, srcb + j), w0b = __shfl(w0, srcb + j + 1);
            float w1a = __shfl(w1, srcb + j), w1b = __shfl(w1, srcb + j + 1);
            u32x2 pa = ((const u32x2*)(o_in + (size_t)sa * 128))[l];
            u32x2 pb = ((const u32x2*)(o_in + (size_t)sb * 128))[l];
            float fa0 = bf2f((u16)(pa.x & 0xffff)), fa1 = bf2f((u16)(pa.x >> 16));
            float fa2 = bf2f((u16)(pa.y & 0xffff)), fa3 = bf2f((u16)(pa.y >> 16));
            float fb0 = bf2f((u16)(pb.x & 0xffff)), fb1 = bf2f((u16)(pb.x >> 16));
            float fb2 = bf2f((u16)(pb.y & 0xffff)), fb3 = bf2f((u16)(pb.y >> 16));
            a00 += w0a * fa0 + w0b * fb0;  a01 += w0a * fa1 + w0b * fb1;
            a02 += w0a * fa2 + w0b * fb2;  a03 += w0a * fa3 + w0b * fb3;
            a10 += w1a * fa0 + w1b * fb0;  a11 += w1a * fa1 + w1b * fb1;
            a12 += w1a * fa2 + w1b * fb2;  a13 += w1a * fa3 + w1b * fb3;
        }
        for (; j < cnt; ++j) {
            int sj = __shfl(s, srcb + j);
            float w0j = __shfl(w0, srcb + j), w1j = __shfl(w1, srcb + j);
            u32x2 pv = ((const u32x2*)(o_in + (size_t)sj * 128))[l];
            float f0 = bf2f((u16)(pv.x & 0xffff)), f1 = bf2f((u16)(pv.x >> 16));
            float f2 = bf2f((u16)(pv.y & 0xffff)), f3 = bf2f((u16)(pv.y >> 16));
            a00 += w0j * f0; a01 += w0j * f1; a02 += w0j * f2; a03 += w0j * f3;
            a10 += w1j * f0; a11 += w1j * f1; a12 += w1j * f2; a13 += w1j * f3;
        }
    }
#pragma unroll
    for (int off = 16; off; off >>= 1) { d0 += __shfl_xor(d0, off); d1 += __shfl_xor(d1, off); }
    float i0 = (d0 > 0.f) ? 1.f / d0 : 0.f, i1 = (d1 > 0.f) ? 1.f / d1 : 0.f;
    u32x2 p0, p1;
    p0.x = (u32)f2bf(a00 * i0) | ((u32)f2bf(a01 * i0) << 16);
    p0.y = (u32)f2bf(a02 * i0) | ((u32)f2bf(a03 * i0) << 16);
    p1.x = (u32)f2bf(a10 * i1) | ((u32)f2bf(a11 * i1) << 16);
    p1.y = (u32)f2bf(a12 * i1) | ((u32)f2bf(a13 * i1) << 16);
    u32x2* aw = (u32x2*)(agg + (size_t)node * 256);
    aw[l] = p0;           // head0 -> cols 0..127
    aw[32 + l] = p1;      // head1 -> cols 128..255
}

// ---------------- mean & var aggregation (interleaved featmv [N,64]), 2 nodes/wave + reparam ----------------
// lane layout within half: l in [0,32); features 2l,2l+1 of interleaved row;
// tbl = l>>4 (0=m,1=v), head = (l>>3)&1.
__global__ __launch_bounds__(256) void k_aggmv(const int* __restrict__ row_ptr, const int* __restrict__ esrc,
                                               const u16* __restrict__ featmv,
                                               const float* __restrict__ elm, const float* __restrict__ erm,
                                               const float* __restrict__ elv, const float* __restrict__ erv,
                                               const float* __restrict__ bm, const float* __restrict__ bv,
                                               const float* __restrict__ eps, float* __restrict__ out, int n) {
    int wave = threadIdx.x >> 6, lane = threadIdx.x & 63;
    int l = lane & 31;
    int node = blockIdx.x * 8 + wave * 2 + (lane >> 5);
    if (node >= n) node = n - 1;
    int tbl = l >> 4, h = (l >> 3) & 1;
    int beg = row_ptr[node], deg = row_ptr[node + 1] - beg;
    float erm0 = erm[2 * node], erm1 = erm[2 * node + 1];
    float erv0 = erv[2 * node], erv1 = erv[2 * node + 1];
    int degmax = max(deg, __shfl_xor(deg, 32));
    const int srcb = lane & 32;
    float acc0 = 0.f, acc1 = 0.f;
    float dm0 = 0.f, dm1 = 0.f, dv0 = 0.f, dv1 = 0.f;
    for (int off0 = 0; off0 < degmax; off0 += 32) {
        float wm0 = 0.f, wm1 = 0.f, wv0 = 0.f, wv1 = 0.f; int s = 0;
        if (off0 + l < deg) {
            s = esrc[beg + off0 + l];
            float2 em = *(const float2*)(elm + 2 * s);
            float2 ev = *(const float2*)(elv + 2 * s);
            wm0 = expf(lrelu(em.x + erm0));
            wm1 = expf(lrelu(em.y + erm1));
            wv0 = expf(lrelu(ev.x + erv0));
            wv1 = expf(lrelu(ev.y + erv1));
        }
        dm0 += wm0; dm1 += wm1; dv0 += wv0; dv1 += wv1;
        int cnt = min(32, degmax - off0);
        int j = 0;
        for (; j + 2 <= cnt; j += 2) {
            int sa = __shfl(s, srcb + j), sb = __shfl(s, srcb + j + 1);
            float am0 = __shfl(wm0, srcb + j), bm0_ = __shfl(wm0, srcb + j + 1);
            float am1 = __shfl(wm1, srcb + j), bm1_ = __shfl(wm1, srcb + j + 1);
            float av0 = __shfl(wv0, srcb + j), bv0_ = __shfl(wv0, srcb + j + 1);
            float av1 = __shfl(wv1, srcb + j), bv1_ = __shfl(wv1, srcb + j + 1);
            float wa = tbl ? (h ? av1 : av0) : (h ? am1 : am0);
            float wb = tbl ? (h ? bv1_ : bv0_) : (h ? bm1_ : bm0_);
            u32 pa = ((const u32*)(featmv + (size_t)sa * 64))[l];
            u32 pb = ((const u32*)(featmv + (size_t)sb * 64))[l];
            acc0 += wa * bf2f((u16)(pa & 0xffff)) + wb * bf2f((u16)(pb & 0xffff));
            acc1 += wa * bf2f((u16)(pa >> 16)) + wb * bf2f((u16)(pb >> 16));
        }
        for (; j < cnt; ++j) {
            int sj = __shfl(s, srcb + j);
            float b0 = __shfl(wm0, srcb + j);
            float b1 = __shfl(wm1, srcb + j);
            float b2 = __shfl(wv0, srcb + j);
            float b3 = __shfl(wv1, srcb + j);
            float wj = tbl ? (h ? b3 : b2) : (h ? b1 : b0);
            u32 pv = ((const u32*)(featmv + (size_t)sj * 64))[l];
            acc0 += wj * bf2f((u16)(pv & 0xffff));
            acc1 += wj * bf2f((u16)(pv >> 16));
        }
    }
#pragma unroll
    for (int off = 16; off; off >>= 1) {
        dm0 += __shfl_xor(dm0, off); dm1 += __shfl_xor(dm1, off);
        dv0 += __shfl_xor(dv0, off); dv1 += __shfl_xor(dv1, off);
    }
    float den = tbl ? (h ? dv1 : dv0) : (h ? dm1 : dm0);
    float inv = (den > 0.f) ? 1.f / den : 0.f;
    const int fidx0 = (2 * l) & 31;                 // table-local col (h*16 + f)
    float bias0 = tbl ? bv[fidx0] : bm[fidx0];
    float bias1 = tbl ? bv[fidx0 + 1] : bm[fidx0 + 1];
    float outc0 = acc0 * inv + bias0;
    float outc1 = acc1 * inv + bias1;
    // head-mean: lanes l and l^8 hold the same (tbl, f) pair for the two heads
    float hm0 = 0.5f * (outc0 + __shfl_xor(outc0, 8));
    float hm1 = 0.5f * (outc1 + __shfl_xor(outc1, 8));
    // var projections live on tbl=1 lanes (16..23 within half)
    int srcv = srcb + 16 + (l & 7);
    float vp0 = __shfl(hm0, srcv);
    float vp1 = __shfl(hm1, srcv);
    if (l < 8) {
        int f0 = 2 * l;
        float var0 = expf(vp0), var1 = expf(vp1);
        float2 e2 = *(const float2*)(eps + (size_t)node * 16 + f0);
        float z0 = hm0 + sqrtf(var0) * e2.x;
        float z1 = hm1 + sqrtf(var1) * e2.y;
        size_t base = (size_t)node * 16 + f0;
        *(float2*)(out + base) = make_float2(z0, z1);
        *(float2*)(out + (size_t)NNODES * 16 + base) = make_float2(hm0, hm1);
        *(float2*)(out + (size_t)2 * NNODES * 16 + base) = make_float2(var0, var1);
    }
}

// ---------------- host ----------------
extern "C" void kernel_launch(void* const* d_in, const int* in_sizes, int n_in,
                              void* d_out, int out_size, void* d_ws, size_t ws_size,
                              hipStream_t stream) {
    const int N = NNODES, E = NEDGES;
    const float* x   = (const float*)d_in[0];
    const int* src   = (const int*)d_in[1];
    const int* dst   = (const int*)d_in[2];
    const float* W1  = (const float*)d_in[3];
    const float* al1 = (const float*)d_in[4];
    const float* ar1 = (const float*)d_in[5];
    const float* b1  = (const float*)d_in[6];
    const float* W2  = (const float*)d_in[7];
    const float* al2 = (const float*)d_in[8];
    const float* ar2 = (const float*)d_in[9];
    const float* b2  = (const float*)d_in[10];
    const float* Wm  = (const float*)d_in[11];
    const float* alm = (const float*)d_in[12];
    const float* arm = (const float*)d_in[13];
    const float* bm  = (const float*)d_in[14];
    const float* Wv  = (const float*)d_in[15];
    const float* alv = (const float*)d_in[16];
    const float* arv = (const float*)d_in[17];
    const float* bv  = (const float*)d_in[18];
    const float* eps = (const float*)d_in[19];
    float* out = (float*)d_out;

    char* ws = (char*)d_ws;
    size_t off = 0;
    auto take = [&](size_t bytes) { size_t r = off; off += (bytes + 255) & ~(size_t)255; return r; };
    int* counts   = (int*)(ws + take((size_t)N * 4));
    int* cursor   = (int*)(ws + take((size_t)N * 4));
    int* row_ptr  = (int*)(ws + take((size_t)(N + 1) * 4));
    int* bsums    = (int*)(ws + take(256 * 4));
    int* esrc     = (int*)(ws + take((size_t)E * 4));
    u16* W1t      = (u16*)(ws + take((size_t)128 * 1000 * 2));
    u16* Wct      = (u16*)(ws + take((size_t)128 * 256 * 2));
    u16* Bmvt     = (u16*)(ws + take((size_t)64 * 128 * 2));
    float* ul2    = (float*)(ws + take(256 * 4));
    float* ur2    = (float*)(ws + take(256 * 4));
    float* bmean  = (float*)(ws + take(128 * 4));
    float* el1    = (float*)(ws + take((size_t)N * 4));
    float* er1    = (float*)(ws + take((size_t)N * 4));
    float* el2    = (float*)(ws + take((size_t)N * 2 * 4));
    float* er2    = (float*)(ws + take((size_t)N * 2 * 4));
    float* elm    = (float*)(ws + take((size_t)N * 2 * 4));
    float* erm    = (float*)(ws + take((size_t)N * 2 * 4));
    float* elv    = (float*)(ws + take((size_t)N * 2 * 4));
    float* erv    = (float*)(ws + take((size_t)N * 2 * 4));
    u16* o_bf     = (u16*)(ws + take((size_t)N * 128 * 2));
    u16* o2_bf    = (u16*)(ws + take((size_t)N * 128 * 2));
    u16* R        = (u16*)(ws + take((size_t)N * 256 * 2));
    u16* feat1    = R;          // layer-1 features [N,128]
    u16* agg      = R;          // layer-2 weighted aggregation of o [N,256] (after feat1 consumed)
    u16* featmv   = R;          // interleaved mv features [N,64] (after agg consumed)
    (void)ws_size; (void)n_in; (void)in_sizes; (void)out_size;

    const int nb = (N + 255) / 256;
    const int eb = (E + 255) / 256;
    const int wb8 = (N + 7) / 8;
    const int gb = (N + 63) / 64;

    // fused weight prep (independent of CSR)
    k_prep<<<dim3(630), 256, 0, stream>>>(W1, W2, Wm, Wv, al2, ar2, b2, W1t, Wct, Bmvt, ul2, ur2, bmean);

    // CSR build
    k_zero2<<<dim3(nb), 256, 0, stream>>>(counts, cursor, N);
    k_count<<<dim3(eb), 256, 0, stream>>>(dst, counts, E);
    k_scan1<<<dim3(nb), 256, 0, stream>>>(counts, row_ptr, bsums, N);
    k_scan2<<<dim3(1), 256, 0, stream>>>(bsums, nb);
    k_scan3<<<dim3(nb), 256, 0, stream>>>(row_ptr, bsums, N, E);
    k_fill<<<dim3(eb), 256, 0, stream>>>(src, dst, row_ptr, cursor, esrc, E);

    // layer 1 (A is f32): GEMM + fused el1/er1
    k_gemm_tiled<float, 0><<<dim3(gb, 1), 256, 0, stream>>>(x, W1t, feat1, N, 128, 1000,
                                                            nullptr, nullptr, al1, ar1, el1, er1);
    k_agg1<<<dim3(wb8), 256, 0, stream>>>(row_ptr, esrc, feat1, el1, er1, b1, ul2, ur2,
                                          o_bf, el2, er2, N);

    // layer 2: aggregate o; project+bias+residual in GEMM epilogue
    k_agg2o<<<dim3(wb8), 256, 0, stream>>>(row_ptr, esrc, o_bf, el2, er2, agg, N);
    k_gemm_tiled<u16, 1><<<dim3(gb, 1), 256, 0, stream>>>(agg, Wct, o2_bf, N, 128, 256,
                                                          bmean, o_bf, nullptr, nullptr, nullptr, nullptr);

    // mean/var: single fused GEMM (m|v) + fused logits
    k_gemmmv<<<dim3(N / 16), 64, 0, stream>>>(o2_bf, Bmvt, featmv, alm, arm, alv, arv,
                                              elm, erm, elv, erv, N);
    k_aggmv<<<dim3(wb8), 256, 0, stream>>>(row_ptr, esrc, featmv, elm, erm, elv, erv,
                                           bm, bv, eps, out, N);
}